// Round 1
// baseline (279.093 us; speedup 1.0000x reference)
//
#include <hip/hip_runtime.h>
#include <hip/hip_bf16.h>

typedef __attribute__((ext_vector_type(8))) __bf16 bf16x8;
typedef __attribute__((ext_vector_type(8))) short s16x8;
typedef __attribute__((ext_vector_type(4))) float f32x4;

#define NB 2
#define NS 4096
#define ND 512
#define NH 8
#define NHD 64
#define NMLP 2048

__device__ __forceinline__ unsigned short f2b(float f) {
  __hip_bfloat16 h = __float2bfloat16(f);
  return __builtin_bit_cast(unsigned short, h);
}

__device__ __forceinline__ float geluf(float x) {
  return 0.5f * x * (1.0f + tanhf(0.7978845608028654f * (x + 0.044715f * x * x * x)));
}

__device__ __forceinline__ void gload16(const void* g, void* l) {
  __builtin_amdgcn_global_load_lds((const __attribute__((address_space(1))) void*)g,
                                   (__attribute__((address_space(3))) void*)l, 16, 0, 0);
}

// ---------------- transpose + bf16 convert: out[C][R] = in[R][C] * scale ----------------
__global__ __launch_bounds__(256) void transp_bf16(const float* __restrict__ in,
                                                   unsigned short* __restrict__ out,
                                                   int lgR, int C, float scale) {
  size_t idx = (size_t)blockIdx.x * 256 + threadIdx.x;
  int R = 1 << lgR;
  int c = (int)(idx >> lgR);
  int r = (int)(idx & (size_t)(R - 1));
  out[idx] = f2b(in[(size_t)r * C + c] * scale);
}

// ---------------- LayerNorm fp32 -> bf16, one wave per row (D=512) ----------------
__global__ __launch_bounds__(256) void ln_bf16(const float* __restrict__ x,
                                               const float* __restrict__ g,
                                               const float* __restrict__ bta,
                                               unsigned short* __restrict__ out) {
  const int t = threadIdx.x, l = t & 63, w = t >> 6;
  const size_t row = (size_t)blockIdx.x * 4 + w;
  const float4* xr = (const float4*)(x + row * ND);
  float4 a = xr[l];
  float4 bq = xr[64 + l];
  float s = a.x + a.y + a.z + a.w + bq.x + bq.y + bq.z + bq.w;
  float ss = a.x * a.x + a.y * a.y + a.z * a.z + a.w * a.w +
             bq.x * bq.x + bq.y * bq.y + bq.z * bq.z + bq.w * bq.w;
#pragma unroll
  for (int msk = 1; msk <= 32; msk <<= 1) {
    s += __shfl_xor(s, msk);
    ss += __shfl_xor(ss, msk);
  }
  float mu = s * (1.0f / ND);
  float var = ss * (1.0f / ND) - mu * mu;
  float rr = rsqrtf(var + 1e-6f);
  const float4* g4 = (const float4*)g;
  const float4* b4 = (const float4*)bta;
  float4 g0 = g4[l], g1 = g4[64 + l], b0 = b4[l], b1 = b4[64 + l];
  ushort4 o0, o1;
  o0.x = f2b((a.x - mu) * rr * g0.x + b0.x);
  o0.y = f2b((a.y - mu) * rr * g0.y + b0.y);
  o0.z = f2b((a.z - mu) * rr * g0.z + b0.z);
  o0.w = f2b((a.w - mu) * rr * g0.w + b0.w);
  o1.x = f2b((bq.x - mu) * rr * g1.x + b1.x);
  o1.y = f2b((bq.y - mu) * rr * g1.y + b1.y);
  o1.z = f2b((bq.z - mu) * rr * g1.z + b1.z);
  o1.w = f2b((bq.w - mu) * rr * g1.w + b1.w);
  ushort4* orow = (ushort4*)(out + row * ND);
  orow[l] = o0;
  orow[64 + l] = o1;
}

// ---------------- MFMA GEMM: C[M][N] = A[M][K] * Bt[N][K]^T, fused epilogues ----------------
// 128x128 tile, BK=32, 256 threads (4 waves, each 64x64), mfma_f32_16x16x32_bf16.
// EPI: 0 = QKV scatter (bf16 -> [3][B][H][S][HD]); 1 = +inputs -> fp32 xres;
//      2 = gelu(+b1) -> bf16; 3 = +b2 +xres -> fp32 out.
template <int EPI>
__global__ __launch_bounds__(256) void gemm_bt(const unsigned short* __restrict__ A,
                                               const unsigned short* __restrict__ Bt,
                                               int M, int N, int K,
                                               unsigned short* __restrict__ ob,
                                               float* __restrict__ of,
                                               const float* __restrict__ addf,
                                               const float* __restrict__ bias) {
  __shared__ unsigned short lA[128 * 32];
  __shared__ unsigned short lB[128 * 32];
  const int t = threadIdx.x;
  const int l = t & 63, w = t >> 6;
  const int wr = w >> 1, wc = w & 1;
  const int bm = blockIdx.y, bn = blockIdx.x;
  const size_t rowBytes = (size_t)K * 2;
  const char* Ab = (const char*)A + (size_t)bm * 128 * rowBytes;
  const char* Bb = (const char*)Bt + (size_t)bn * 128 * rowBytes;
  const int o0 = t * 16, o1 = t * 16 + 4096;
  const int r0 = o0 >> 6, c0 = o0 & 63;
  const int r1 = o1 >> 6, c1 = o1 & 63;
  f32x4 acc[4][4] = {};
  for (int k0 = 0; k0 < K; k0 += 32) {
    __syncthreads();
    gload16(Ab + (size_t)r0 * rowBytes + 2 * k0 + c0, (char*)lA + o0);
    gload16(Ab + (size_t)r1 * rowBytes + 2 * k0 + c1, (char*)lA + o1);
    gload16(Bb + (size_t)r0 * rowBytes + 2 * k0 + c0, (char*)lB + o0);
    gload16(Bb + (size_t)r1 * rowBytes + 2 * k0 + c1, (char*)lB + o1);
    __syncthreads();
    bf16x8 aF[4], bF[4];
#pragma unroll
    for (int m = 0; m < 4; ++m)
      aF[m] = *(const bf16x8*)&lA[(wr * 64 + m * 16 + (l & 15)) * 32 + (l >> 4) * 8];
#pragma unroll
    for (int n = 0; n < 4; ++n)
      bF[n] = *(const bf16x8*)&lB[(wc * 64 + n * 16 + (l & 15)) * 32 + (l >> 4) * 8];
#pragma unroll
    for (int m = 0; m < 4; ++m)
#pragma unroll
      for (int n = 0; n < 4; ++n)
        acc[m][n] = __builtin_amdgcn_mfma_f32_16x16x32_bf16(aF[m], bF[n], acc[m][n], 0, 0, 0);
  }
#pragma unroll
  for (int m = 0; m < 4; ++m)
#pragma unroll
    for (int n = 0; n < 4; ++n)
#pragma unroll
      for (int j = 0; j < 4; ++j) {
        int row = bm * 128 + wr * 64 + m * 16 + (l >> 4) * 4 + j;
        int col = bn * 128 + wc * 64 + n * 16 + (l & 15);
        float v = acc[m][n][j];
        if constexpr (EPI == 0) {
          int part = col >> 9, nn = col & 511;
          int hh = nn >> 6, hd = nn & 63;
          int b = row >> 12, sidx = row & 4095;
          ob[((((size_t)part * NB + b) * NH + hh) * NS + sidx) * NHD + hd] = f2b(v);
        } else if constexpr (EPI == 1) {
          size_t i = (size_t)row * ND + col;
          of[i] = v + addf[i];
        } else if constexpr (EPI == 2) {
          size_t i = (size_t)row * NMLP + col;
          ob[i] = f2b(geluf(v + bias[col]));
        } else {
          size_t i = (size_t)row * ND + col;
          of[i] = v + bias[col] + addf[i];
        }
      }
}

// ---------------- block-sparse flash attention ----------------
// grid = B*H*32 blocks; block handles one (b, h, 128-row q-block); 4 waves x 32 q-rows.
// Keys per q-block: qb summary chunks (rows t*128+96..+32 for t<qb) + 4 local causal chunks.
__global__ __launch_bounds__(256) void attn_sparse(const unsigned short* __restrict__ qm,
                                                   const unsigned short* __restrict__ km,
                                                   const unsigned short* __restrict__ vm,
                                                   unsigned short* __restrict__ ctx) {
  __shared__ unsigned short kl[32 * 72];   // K chunk [32][64] padded to 72
  __shared__ unsigned short vt[64 * 40];   // V chunk transposed [64][32] padded to 40
  __shared__ unsigned short pl[4][32 * 40]; // per-wave P [32][32] padded to 40
  const int t = threadIdx.x, l = t & 63, w = t >> 6;
  const int bid = blockIdx.x;
  const int qb = bid & 31, hh = (bid >> 5) & 7, b = bid >> 8;
  const size_t bh = ((size_t)b * NH + hh) * NS;
  // Q fragments (held in registers for the whole kernel); q already scaled by 1/8.
  bf16x8 qa[2][2];
  const int qrow0 = qb * 128 + w * 32;
#pragma unroll
  for (int m = 0; m < 2; ++m)
#pragma unroll
    for (int ks = 0; ks < 2; ++ks)
      qa[m][ks] = *(const bf16x8*)&qm[(bh + qrow0 + m * 16 + (l & 15)) * NHD + ks * 32 + (l >> 4) * 8];
  f32x4 c[2][4] = {};
  float mrun[2][4], lrun[2][4];
#pragma unroll
  for (int m = 0; m < 2; ++m)
#pragma unroll
    for (int j = 0; j < 4; ++j) { mrun[m][j] = -1e30f; lrun[m][j] = 0.0f; }

  const int nsum = qb, nch = qb + 4;
  const int sr = t >> 3, sc8 = (t & 7) * 8;  // staging: 8 threads per key-row
  for (int ch = 0; ch < nch; ++ch) {
    const int kbase = (ch < nsum) ? (ch * 128 + 96) : (qb * 128 + (ch - nsum) * 32);
    __syncthreads();  // protect LDS reuse across chunks
    {
      const s16x8 kv8 = *(const s16x8*)&km[(bh + kbase + sr) * NHD + sc8];
      *(s16x8*)&kl[sr * 72 + sc8] = kv8;
      const s16x8 vv8 = *(const s16x8*)&vm[(bh + kbase + sr) * NHD + sc8];
#pragma unroll
      for (int jj = 0; jj < 8; ++jj)
        vt[(sc8 + jj) * 40 + sr] = (unsigned short)vv8[jj];
    }
    __syncthreads();
    const int lc = ch - nsum;
    if (ch >= nsum && lc > w) continue;  // fully masked for this wave
    // S = Q * Kchunk^T  [32 q][32 keys]
    bf16x8 kbf[2][2];
#pragma unroll
    for (int n = 0; n < 2; ++n)
#pragma unroll
      for (int ks = 0; ks < 2; ++ks)
        kbf[n][ks] = *(const bf16x8*)&kl[(n * 16 + (l & 15)) * 72 + ks * 32 + (l >> 4) * 8];
    f32x4 sf[2][2] = {};
#pragma unroll
    for (int m = 0; m < 2; ++m)
#pragma unroll
      for (int n = 0; n < 2; ++n) {
        sf[m][n] = __builtin_amdgcn_mfma_f32_16x16x32_bf16(qa[m][0], kbf[n][0], sf[m][n], 0, 0, 0);
        sf[m][n] = __builtin_amdgcn_mfma_f32_16x16x32_bf16(qa[m][1], kbf[n][1], sf[m][n], 0, 0, 0);
      }
    if (ch >= nsum && lc == w) {  // diagonal chunk: causal mask
#pragma unroll
      for (int m = 0; m < 2; ++m)
#pragma unroll
        for (int n = 0; n < 2; ++n)
#pragma unroll
          for (int j = 0; j < 4; ++j) {
            int keyg = kbase + n * 16 + (l & 15);
            int rowg = qb * 128 + w * 32 + m * 16 + (l >> 4) * 4 + j;
            if (keyg > rowg) sf[m][n][j] = -1e9f;
          }
    }
    // online softmax (rows live across 16-lane groups; reduce over l&15)
#pragma unroll
    for (int m = 0; m < 2; ++m) {
      float cm[4], al[4], nm[4];
#pragma unroll
      for (int j = 0; j < 4; ++j) {
        cm[j] = fmaxf(sf[m][0][j], sf[m][1][j]);
        cm[j] = fmaxf(cm[j], __shfl_xor(cm[j], 1));
        cm[j] = fmaxf(cm[j], __shfl_xor(cm[j], 2));
        cm[j] = fmaxf(cm[j], __shfl_xor(cm[j], 4));
        cm[j] = fmaxf(cm[j], __shfl_xor(cm[j], 8));
        nm[j] = fmaxf(mrun[m][j], cm[j]);
        al[j] = __expf(mrun[m][j] - nm[j]);
        mrun[m][j] = nm[j];
      }
#pragma unroll
      for (int n = 0; n < 4; ++n)
#pragma unroll
        for (int j = 0; j < 4; ++j) c[m][n][j] *= al[j];
      float rs[4] = {0.f, 0.f, 0.f, 0.f};
#pragma unroll
      for (int n = 0; n < 2; ++n)
#pragma unroll
        for (int j = 0; j < 4; ++j) {
          float p = __expf(sf[m][n][j] - nm[j]);
          sf[m][n][j] = p;
          rs[j] += p;
        }
#pragma unroll
      for (int j = 0; j < 4; ++j) {
        rs[j] += __shfl_xor(rs[j], 1);
        rs[j] += __shfl_xor(rs[j], 2);
        rs[j] += __shfl_xor(rs[j], 4);
        rs[j] += __shfl_xor(rs[j], 8);
        lrun[m][j] = lrun[m][j] * al[j] + rs[j];
      }
#pragma unroll
      for (int n = 0; n < 2; ++n)
#pragma unroll
        for (int j = 0; j < 4; ++j)
          pl[w][(m * 16 + (l >> 4) * 4 + j) * 40 + n * 16 + (l & 15)] = f2b(sf[m][n][j]);
    }
    // PV: ctx += P[32 q][32 k] * V[32 k][64]
    bf16x8 pa[2], vb[4];
#pragma unroll
    for (int m = 0; m < 2; ++m)
      pa[m] = *(const bf16x8*)&pl[w][(m * 16 + (l & 15)) * 40 + (l >> 4) * 8];
#pragma unroll
    for (int n = 0; n < 4; ++n)
      vb[n] = *(const bf16x8*)&vt[(n * 16 + (l & 15)) * 40 + (l >> 4) * 8];
#pragma unroll
    for (int m = 0; m < 2; ++m)
#pragma unroll
      for (int n = 0; n < 4; ++n)
        c[m][n] = __builtin_amdgcn_mfma_f32_16x16x32_bf16(pa[m], vb[n], c[m][n], 0, 0, 0);
  }
  // write ctx as [B][S][H*HD] bf16
#pragma unroll
  for (int m = 0; m < 2; ++m)
#pragma unroll
    for (int n = 0; n < 4; ++n)
#pragma unroll
      for (int j = 0; j < 4; ++j) {
        int srow = qb * 128 + w * 32 + m * 16 + (l >> 4) * 4 + j;
        int col = n * 16 + (l & 15);
        ctx[((size_t)b * NS + srow) * ND + hh * NHD + col] = f2b(c[m][n][j] / lrun[m][j]);
      }
}

extern "C" void kernel_launch(void* const* d_in, const int* in_sizes, int n_in,
                              void* d_out, int out_size, void* d_ws, size_t ws_size,
                              hipStream_t stream) {
  (void)in_sizes; (void)n_in; (void)out_size; (void)ws_size;
  const float* inputs = (const float*)d_in[0];
  const float* ln1s = (const float*)d_in[1];
  const float* ln1b = (const float*)d_in[2];
  const float* wq = (const float*)d_in[3];
  const float* wk = (const float*)d_in[4];
  const float* wv = (const float*)d_in[5];
  const float* wo = (const float*)d_in[6];
  const float* ln2s = (const float*)d_in[7];
  const float* ln2b = (const float*)d_in[8];
  const float* w1 = (const float*)d_in[9];
  const float* b1 = (const float*)d_in[10];
  const float* w2 = (const float*)d_in[11];
  const float* b2 = (const float*)d_in[12];
  float* out = (float*)d_out;

  // workspace layout (bytes): ~102 MB total
  unsigned short* xln = (unsigned short*)d_ws;                 // 8192*512 bf16
  unsigned short* xln2 = xln + (size_t)8192 * 512;             // 8192*512
  unsigned short* ctx = xln2 + (size_t)8192 * 512;             // 8192*512
  unsigned short* qkv = ctx + (size_t)8192 * 512;              // 3 * 8192*512
  float* xres = (float*)(qkv + (size_t)3 * 8192 * 512);        // 8192*512 fp32
  unsigned short* hbuf = (unsigned short*)(xres + (size_t)8192 * 512);  // 8192*2048
  unsigned short* qkvT = hbuf + (size_t)8192 * 2048;           // 1536*512
  unsigned short* woT = qkvT + (size_t)1536 * 512;             // 512*512
  unsigned short* w1T = woT + (size_t)512 * 512;               // 2048*512
  unsigned short* w2T = w1T + (size_t)2048 * 512;              // 512*2048

  // weight transposes to B^T bf16 (q scale 1/sqrt(64) baked into wq^T)
  transp_bf16<<<1024, 256, 0, stream>>>(wq, qkvT, 9, 512, 0.125f);
  transp_bf16<<<1024, 256, 0, stream>>>(wk, qkvT + (size_t)512 * 512, 9, 512, 1.0f);
  transp_bf16<<<1024, 256, 0, stream>>>(wv, qkvT + (size_t)1024 * 512, 9, 512, 1.0f);
  transp_bf16<<<1024, 256, 0, stream>>>(wo, woT, 9, 512, 1.0f);
  transp_bf16<<<4096, 256, 0, stream>>>(w1, w1T, 9, 2048, 1.0f);
  transp_bf16<<<4096, 256, 0, stream>>>(w2, w2T, 11, 512, 1.0f);

  ln_bf16<<<2048, 256, 0, stream>>>(inputs, ln1s, ln1b, xln);
  gemm_bt<0><<<dim3(12, 64), 256, 0, stream>>>(xln, qkvT, 8192, 1536, 512,
                                               qkv, nullptr, nullptr, nullptr);
  attn_sparse<<<512, 256, 0, stream>>>(qkv, qkv + (size_t)8192 * 512,
                                       qkv + (size_t)2 * 8192 * 512, ctx);
  gemm_bt<1><<<dim3(4, 64), 256, 0, stream>>>(ctx, woT, 8192, 512, 512,
                                              nullptr, xres, inputs, nullptr);
  ln_bf16<<<2048, 256, 0, stream>>>(xres, ln2s, ln2b, xln2);
  gemm_bt<2><<<dim3(16, 64), 256, 0, stream>>>(xln2, w1T, 8192, 2048, 512,
                                               hbuf, nullptr, nullptr, b1);
  gemm_bt<3><<<dim3(4, 64), 256, 0, stream>>>(hbuf, w2T, 8192, 512, 2048,
                                              nullptr, out, xres, b2);
}

// Round 2
// 210.785 us; speedup vs baseline: 1.3241x; 1.3241x over previous
//
#include <hip/hip_runtime.h>
#include <hip/hip_bf16.h>

typedef __attribute__((ext_vector_type(8))) __bf16 bf16x8;
typedef __attribute__((ext_vector_type(8))) short s16x8;
typedef __attribute__((ext_vector_type(4))) float f32x4;

#define NB 2
#define NS 4096
#define ND 512
#define NH 8
#define NHD 64
#define NMLP 2048

__device__ __forceinline__ unsigned short f2b(float f) {
  __hip_bfloat16 h = __float2bfloat16(f);
  return __builtin_bit_cast(unsigned short, h);
}

__device__ __forceinline__ float geluf(float x) {
  return 0.5f * x * (1.0f + tanhf(0.7978845608028654f * (x + 0.044715f * x * x * x)));
}

__device__ __forceinline__ void gload16(const void* g, void* l) {
  __builtin_amdgcn_global_load_lds((const __attribute__((address_space(1))) void*)g,
                                   (__attribute__((address_space(3))) void*)l, 16, 0, 0);
}

// ---------------- all weight transposes fused into one launch ----------------
// segment map (element idx over bf16 outputs):
//   [0,2^18)       wq -> qkvT[0]      (scale 1/8 baked in)
//   [2^18,2^19)    wk -> qkvT[512*512]
//   [2^19,3*2^18)  wv -> qkvT[2*512*512]
//   [3*2^18,2^20)  wo -> woT
//   [2^20,2^21)    w1 [512][2048] -> w1T [2048][512]
//   [2^21,3*2^20)  w2 [2048][512] -> w2T [512][2048]
__global__ __launch_bounds__(256) void prep_weights(const float* __restrict__ wq,
                                                    const float* __restrict__ wk,
                                                    const float* __restrict__ wv,
                                                    const float* __restrict__ wo,
                                                    const float* __restrict__ w1,
                                                    const float* __restrict__ w2,
                                                    unsigned short* __restrict__ qkvT,
                                                    unsigned short* __restrict__ woT,
                                                    unsigned short* __restrict__ w1T,
                                                    unsigned short* __restrict__ w2T) {
  size_t idx = (size_t)blockIdx.x * 256 + threadIdx.x;
  if (idx < (1u << 20)) {
    int seg = (int)(idx >> 18);
    int o = (int)(idx & ((1 << 18) - 1));
    const float* src = seg == 0 ? wq : seg == 1 ? wk : seg == 2 ? wv : wo;
    unsigned short* dst = (seg < 3) ? (qkvT + ((size_t)seg << 18)) : woT;
    float sc = (seg == 0) ? 0.125f : 1.0f;
    int c = o >> 9, r = o & 511;
    dst[o] = f2b(src[(size_t)r * 512 + c] * sc);
  } else if (idx < (2u << 20)) {
    int o = (int)(idx - (1u << 20));
    int c = o >> 9, r = o & 511;
    w1T[o] = f2b(w1[(size_t)r * 2048 + c]);
  } else {
    int o = (int)(idx - (2u << 20));
    int c = o >> 11, r = o & 2047;
    w2T[o] = f2b(w2[(size_t)r * 512 + c]);
  }
}

// ---------------- LayerNorm fp32 -> bf16, one wave per row (D=512) ----------------
__global__ __launch_bounds__(256) void ln_bf16(const float* __restrict__ x,
                                               const float* __restrict__ g,
                                               const float* __restrict__ bta,
                                               unsigned short* __restrict__ out) {
  const int t = threadIdx.x, l = t & 63, w = t >> 6;
  const size_t row = (size_t)blockIdx.x * 4 + w;
  const float4* xr = (const float4*)(x + row * ND);
  float4 a = xr[l];
  float4 bq = xr[64 + l];
  float s = a.x + a.y + a.z + a.w + bq.x + bq.y + bq.z + bq.w;
  float ss = a.x * a.x + a.y * a.y + a.z * a.z + a.w * a.w +
             bq.x * bq.x + bq.y * bq.y + bq.z * bq.z + bq.w * bq.w;
#pragma unroll
  for (int msk = 1; msk <= 32; msk <<= 1) {
    s += __shfl_xor(s, msk);
    ss += __shfl_xor(ss, msk);
  }
  float mu = s * (1.0f / ND);
  float var = ss * (1.0f / ND) - mu * mu;
  float rr = rsqrtf(var + 1e-6f);
  const float4* g4 = (const float4*)g;
  const float4* b4 = (const float4*)bta;
  float4 g0 = g4[l], g1 = g4[64 + l], b0 = b4[l], b1 = b4[64 + l];
  ushort4 o0, o1;
  o0.x = f2b((a.x - mu) * rr * g0.x + b0.x);
  o0.y = f2b((a.y - mu) * rr * g0.y + b0.y);
  o0.z = f2b((a.z - mu) * rr * g0.z + b0.z);
  o0.w = f2b((a.w - mu) * rr * g0.w + b0.w);
  o1.x = f2b((bq.x - mu) * rr * g1.x + b1.x);
  o1.y = f2b((bq.y - mu) * rr * g1.y + b1.y);
  o1.z = f2b((bq.z - mu) * rr * g1.z + b1.z);
  o1.w = f2b((bq.w - mu) * rr * g1.w + b1.w);
  ushort4* orow = (ushort4*)(out + row * ND);
  orow[l] = o0;
  orow[64 + l] = o1;
}

// ---------------- MFMA GEMM: C[M][N] = A[M][K] * Bt[N][K]^T, fused epilogues ----------------
template <int EPI>
__global__ __launch_bounds__(256) void gemm_bt(const unsigned short* __restrict__ A,
                                               const unsigned short* __restrict__ Bt,
                                               int M, int N, int K,
                                               unsigned short* __restrict__ ob,
                                               float* __restrict__ of,
                                               const float* __restrict__ addf,
                                               const float* __restrict__ bias) {
  __shared__ unsigned short lA[128 * 32];
  __shared__ unsigned short lB[128 * 32];
  const int t = threadIdx.x;
  const int l = t & 63, w = t >> 6;
  const int wr = w >> 1, wc = w & 1;
  const int bm = blockIdx.y, bn = blockIdx.x;
  const size_t rowBytes = (size_t)K * 2;
  const char* Ab = (const char*)A + (size_t)bm * 128 * rowBytes;
  const char* Bb = (const char*)Bt + (size_t)bn * 128 * rowBytes;
  const int o0 = t * 16, o1 = t * 16 + 4096;
  const int r0 = o0 >> 6, c0 = o0 & 63;
  const int r1 = o1 >> 6, c1 = o1 & 63;
  f32x4 acc[4][4] = {};
  for (int k0 = 0; k0 < K; k0 += 32) {
    __syncthreads();
    gload16(Ab + (size_t)r0 * rowBytes + 2 * k0 + c0, (char*)lA + o0);
    gload16(Ab + (size_t)r1 * rowBytes + 2 * k0 + c1, (char*)lA + o1);
    gload16(Bb + (size_t)r0 * rowBytes + 2 * k0 + c0, (char*)lB + o0);
    gload16(Bb + (size_t)r1 * rowBytes + 2 * k0 + c1, (char*)lB + o1);
    __syncthreads();
    bf16x8 aF[4], bF[4];
#pragma unroll
    for (int m = 0; m < 4; ++m)
      aF[m] = *(const bf16x8*)&lA[(wr * 64 + m * 16 + (l & 15)) * 32 + (l >> 4) * 8];
#pragma unroll
    for (int n = 0; n < 4; ++n)
      bF[n] = *(const bf16x8*)&lB[(wc * 64 + n * 16 + (l & 15)) * 32 + (l >> 4) * 8];
#pragma unroll
    for (int m = 0; m < 4; ++m)
#pragma unroll
      for (int n = 0; n < 4; ++n)
        acc[m][n] = __builtin_amdgcn_mfma_f32_16x16x32_bf16(aF[m], bF[n], acc[m][n], 0, 0, 0);
  }
#pragma unroll
  for (int m = 0; m < 4; ++m)
#pragma unroll
    for (int n = 0; n < 4; ++n)
#pragma unroll
      for (int j = 0; j < 4; ++j) {
        int row = bm * 128 + wr * 64 + m * 16 + (l >> 4) * 4 + j;
        int col = bn * 128 + wc * 64 + n * 16 + (l & 15);
        float v = acc[m][n][j];
        if constexpr (EPI == 0) {
          int part = col >> 9, nn = col & 511;
          int hh = nn >> 6, hd = nn & 63;
          int b = row >> 12, sidx = row & 4095;
          ob[((((size_t)part * NB + b) * NH + hh) * NS + sidx) * NHD + hd] = f2b(v);
        } else if constexpr (EPI == 1) {
          size_t i = (size_t)row * ND + col;
          of[i] = v + addf[i];
        } else if constexpr (EPI == 2) {
          size_t i = (size_t)row * NMLP + col;
          ob[i] = f2b(geluf(v + bias[col]));
        } else {
          size_t i = (size_t)row * ND + col;
          of[i] = v + bias[col] + addf[i];
        }
      }
}

// ---------------- block-sparse flash attention, 8 waves x 16 q-rows, 64-key chunks ----------------
// grid = B*H*32 blocks; block = (b, h, 128-row q-block). For b=1 the q-block index is
// complement-remapped (qb' = 31-qb) so co-resident blocks (bid, bid+256) have constant
// total work. Summary keys (cols j%128>=96, block t<qb) staged as 64-key chunks (two
// 32-row segments); local 128 keys = 2 causal 64-key chunks.
__global__ __launch_bounds__(512) void attn_sparse(const unsigned short* __restrict__ qm,
                                                   const unsigned short* __restrict__ km,
                                                   const unsigned short* __restrict__ vm,
                                                   unsigned short* __restrict__ ctx) {
  __shared__ unsigned short kl[64 * 72];    // K chunk [64 keys][64 d] padded
  __shared__ unsigned short vt[64 * 72];    // V chunk transposed [64 d][64 keys] padded
  __shared__ unsigned short pl[8][16 * 72]; // per-wave P [16 q][64 keys] padded
  const int t = threadIdx.x, l = t & 63, w = t >> 6;
  const int bid = blockIdx.x;
  const int qbRaw = bid & 31, hh = (bid >> 5) & 7, b = bid >> 8;
  const int qb = b ? (31 - qbRaw) : qbRaw;
  const size_t bh = ((size_t)b * NH + hh) * NS;
  // Q fragments for this wave's 16 rows (q pre-scaled by 1/8 via wq)
  const int qrow0 = qb * 128 + w * 16;
  bf16x8 qa[2];
#pragma unroll
  for (int ks = 0; ks < 2; ++ks)
    qa[ks] = *(const bf16x8*)&qm[(bh + qrow0 + (l & 15)) * NHD + ks * 32 + (l >> 4) * 8];
  f32x4 c[4] = {};
  float mrun[4], lrun[4];
#pragma unroll
  for (int j = 0; j < 4; ++j) { mrun[j] = -1e30f; lrun[j] = 0.0f; }

  const int nsum = (qb + 1) >> 1;      // 64-key summary chunks (last partial if qb odd)
  const int partial = qb & 1;
  const int nch = nsum + 2;
  const int skey = t >> 3, sd0 = (t & 7) * 8;  // staging: 8 threads per key row

  for (int ch = 0; ch < nch; ++ch) {
    __syncthreads();  // previous chunk's compute done before LDS overwrite
    {
      int gr;
      if (ch < nsum) gr = (ch * 2 + (skey >> 5)) * 128 + 96 + (skey & 31);
      else gr = qb * 128 + (ch - nsum) * 64 + skey;
      const s16x8 kv8 = *(const s16x8*)&km[(bh + gr) * NHD + sd0];
      *(s16x8*)&kl[skey * 72 + sd0] = kv8;
      const s16x8 vv8 = *(const s16x8*)&vm[(bh + gr) * NHD + sd0];
#pragma unroll
      for (int jj = 0; jj < 8; ++jj)
        vt[(sd0 + jj) * 72 + skey] = (unsigned short)vv8[jj];
    }
    __syncthreads();
    const int lc = ch - nsum;
    if (ch >= nsum && lc * 64 > w * 16 + 15) continue;  // fully above diagonal
    // S = Q * K^T : [16 q][64 keys]
    bf16x8 kb[4][2];
#pragma unroll
    for (int n = 0; n < 4; ++n)
#pragma unroll
      for (int ks = 0; ks < 2; ++ks)
        kb[n][ks] = *(const bf16x8*)&kl[(n * 16 + (l & 15)) * 72 + ks * 32 + (l >> 4) * 8];
    f32x4 sf[4] = {};
#pragma unroll
    for (int n = 0; n < 4; ++n) {
      sf[n] = __builtin_amdgcn_mfma_f32_16x16x32_bf16(qa[0], kb[n][0], sf[n], 0, 0, 0);
      sf[n] = __builtin_amdgcn_mfma_f32_16x16x32_bf16(qa[1], kb[n][1], sf[n], 0, 0, 0);
    }
    // masking
    if (ch < nsum) {
      if (partial && ch == nsum - 1) {  // keys 32..63 belong to local block
#pragma unroll
        for (int n = 2; n < 4; ++n)
#pragma unroll
          for (int j = 0; j < 4; ++j) sf[n][j] = -1e9f;
      }
    } else if (lc * 64 + 63 > w * 16) {  // causal mask needed
#pragma unroll
      for (int n = 0; n < 4; ++n)
#pragma unroll
        for (int j = 0; j < 4; ++j) {
          int keyRel = lc * 64 + n * 16 + (l & 15);
          int rowRel = w * 16 + (l >> 4) * 4 + j;
          if (keyRel > rowRel) sf[n][j] = -1e9f;
        }
    }
    // online softmax (rows spread over (l>>4)*4+j; keys over n and l&15)
    float cm[4], al[4];
#pragma unroll
    for (int j = 0; j < 4; ++j) {
      cm[j] = fmaxf(fmaxf(sf[0][j], sf[1][j]), fmaxf(sf[2][j], sf[3][j]));
      cm[j] = fmaxf(cm[j], __shfl_xor(cm[j], 1));
      cm[j] = fmaxf(cm[j], __shfl_xor(cm[j], 2));
      cm[j] = fmaxf(cm[j], __shfl_xor(cm[j], 4));
      cm[j] = fmaxf(cm[j], __shfl_xor(cm[j], 8));
      float nm = fmaxf(mrun[j], cm[j]);
      al[j] = __expf(mrun[j] - nm);
      mrun[j] = nm;
    }
#pragma unroll
    for (int n = 0; n < 4; ++n)
#pragma unroll
      for (int j = 0; j < 4; ++j) c[n][j] *= al[j];
    float rs[4] = {0.f, 0.f, 0.f, 0.f};
#pragma unroll
    for (int n = 0; n < 4; ++n)
#pragma unroll
      for (int j = 0; j < 4; ++j) {
        float p = __expf(sf[n][j] - mrun[j]);
        sf[n][j] = p;
        rs[j] += p;
      }
#pragma unroll
    for (int j = 0; j < 4; ++j) {
      rs[j] += __shfl_xor(rs[j], 1);
      rs[j] += __shfl_xor(rs[j], 2);
      rs[j] += __shfl_xor(rs[j], 4);
      rs[j] += __shfl_xor(rs[j], 8);
      lrun[j] = lrun[j] * al[j] + rs[j];
    }
#pragma unroll
    for (int n = 0; n < 4; ++n)
#pragma unroll
      for (int j = 0; j < 4; ++j)
        pl[w][((l >> 4) * 4 + j) * 72 + n * 16 + (l & 15)] = f2b(sf[n][j]);
    // PV: c[16 q][64 d] += P[16 q][64 k] * V[64 k][64 d]
    bf16x8 pa[2], vb[4][2];
#pragma unroll
    for (int ks = 0; ks < 2; ++ks)
      pa[ks] = *(const bf16x8*)&pl[w][(l & 15) * 72 + ks * 32 + (l >> 4) * 8];
#pragma unroll
    for (int n = 0; n < 4; ++n)
#pragma unroll
      for (int ks = 0; ks < 2; ++ks)
        vb[n][ks] = *(const bf16x8*)&vt[(n * 16 + (l & 15)) * 72 + ks * 32 + (l >> 4) * 8];
#pragma unroll
    for (int n = 0; n < 4; ++n) {
      c[n] = __builtin_amdgcn_mfma_f32_16x16x32_bf16(pa[0], vb[n][0], c[n], 0, 0, 0);
      c[n] = __builtin_amdgcn_mfma_f32_16x16x32_bf16(pa[1], vb[n][1], c[n], 0, 0, 0);
    }
  }
  // write ctx as [B][S][H*HD] bf16
#pragma unroll
  for (int n = 0; n < 4; ++n)
#pragma unroll
    for (int j = 0; j < 4; ++j) {
      int srow = qrow0 + (l >> 4) * 4 + j;
      int col = n * 16 + (l & 15);
      ctx[((size_t)b * NS + srow) * ND + hh * NHD + col] = f2b(c[n][j] / lrun[j]);
    }
}

extern "C" void kernel_launch(void* const* d_in, const int* in_sizes, int n_in,
                              void* d_out, int out_size, void* d_ws, size_t ws_size,
                              hipStream_t stream) {
  (void)in_sizes; (void)n_in; (void)out_size; (void)ws_size;
  const float* inputs = (const float*)d_in[0];
  const float* ln1s = (const float*)d_in[1];
  const float* ln1b = (const float*)d_in[2];
  const float* wq = (const float*)d_in[3];
  const float* wk = (const float*)d_in[4];
  const float* wv = (const float*)d_in[5];
  const float* wo = (const float*)d_in[6];
  const float* ln2s = (const float*)d_in[7];
  const float* ln2b = (const float*)d_in[8];
  const float* w1 = (const float*)d_in[9];
  const float* b1 = (const float*)d_in[10];
  const float* w2 = (const float*)d_in[11];
  const float* b2 = (const float*)d_in[12];
  float* out = (float*)d_out;

  // workspace layout (~102 MB)
  unsigned short* xln = (unsigned short*)d_ws;                 // 8192*512 bf16
  unsigned short* xln2 = xln + (size_t)8192 * 512;             // 8192*512
  unsigned short* ctx = xln2 + (size_t)8192 * 512;             // 8192*512
  unsigned short* qkv = ctx + (size_t)8192 * 512;              // 3 * 8192*512
  float* xres = (float*)(qkv + (size_t)3 * 8192 * 512);        // 8192*512 fp32
  unsigned short* hbuf = (unsigned short*)(xres + (size_t)8192 * 512);  // 8192*2048
  unsigned short* qkvT = hbuf + (size_t)8192 * 2048;           // 1536*512
  unsigned short* woT = qkvT + (size_t)1536 * 512;             // 512*512
  unsigned short* w1T = woT + (size_t)512 * 512;               // 2048*512
  unsigned short* w2T = w1T + (size_t)2048 * 512;              // 512*2048

  prep_weights<<<12288, 256, 0, stream>>>(wq, wk, wv, wo, w1, w2, qkvT, woT, w1T, w2T);
  ln_bf16<<<2048, 256, 0, stream>>>(inputs, ln1s, ln1b, xln);
  gemm_bt<0><<<dim3(12, 64), 256, 0, stream>>>(xln, qkvT, 8192, 1536, 512,
                                               qkv, nullptr, nullptr, nullptr);
  attn_sparse<<<512, 512, 0, stream>>>(qkv, qkv + (size_t)8192 * 512,
                                       qkv + (size_t)2 * 8192 * 512, ctx);
  gemm_bt<1><<<dim3(4, 64), 256, 0, stream>>>(ctx, woT, 8192, 512, 512,
                                              nullptr, xres, inputs, nullptr);
  ln_bf16<<<2048, 256, 0, stream>>>(xres, ln2s, ln2b, xln2);
  gemm_bt<2><<<dim3(16, 64), 256, 0, stream>>>(xln2, w1T, 8192, 2048, 512,
                                               hbuf, nullptr, nullptr, b1);
  gemm_bt<3><<<dim3(4, 64), 256, 0, stream>>>(hbuf, w2T, 8192, 512, 2048,
                                              nullptr, out, xres, b2);
}

// Round 3
// 187.247 us; speedup vs baseline: 1.4905x; 1.1257x over previous
//
#include <hip/hip_runtime.h>
#include <hip/hip_bf16.h>

typedef __attribute__((ext_vector_type(8))) __bf16 bf16x8;
typedef __attribute__((ext_vector_type(8))) short s16x8;
typedef __attribute__((ext_vector_type(4))) float f32x4;

#define NB 2
#define NS 4096
#define ND 512
#define NH 8
#define NHD 64
#define NMLP 2048

__device__ __forceinline__ unsigned short f2b(float f) {
  __hip_bfloat16 h = __float2bfloat16(f);
  return __builtin_bit_cast(unsigned short, h);
}

__device__ __forceinline__ float geluf(float x) {
  return 0.5f * x * (1.0f + tanhf(0.7978845608028654f * (x + 0.044715f * x * x * x)));
}

__device__ __forceinline__ void gload16(const void* g, void* l) {
  __builtin_amdgcn_global_load_lds((const __attribute__((address_space(1))) void*)g,
                                   (__attribute__((address_space(3))) void*)l, 16, 0, 0);
}

// ---------------- all weight transposes fused into one launch ----------------
__global__ __launch_bounds__(256) void prep_weights(const float* __restrict__ wq,
                                                    const float* __restrict__ wk,
                                                    const float* __restrict__ wv,
                                                    const float* __restrict__ wo,
                                                    const float* __restrict__ w1,
                                                    const float* __restrict__ w2,
                                                    unsigned short* __restrict__ qkvT,
                                                    unsigned short* __restrict__ woT,
                                                    unsigned short* __restrict__ w1T,
                                                    unsigned short* __restrict__ w2T) {
  size_t idx = (size_t)blockIdx.x * 256 + threadIdx.x;
  if (idx < (1u << 20)) {
    int seg = (int)(idx >> 18);
    int o = (int)(idx & ((1 << 18) - 1));
    const float* src = seg == 0 ? wq : seg == 1 ? wk : seg == 2 ? wv : wo;
    unsigned short* dst = (seg < 3) ? (qkvT + ((size_t)seg << 18)) : woT;
    float sc = (seg == 0) ? 0.125f : 1.0f;
    int c = o >> 9, r = o & 511;
    dst[o] = f2b(src[(size_t)r * 512 + c] * sc);
  } else if (idx < (2u << 20)) {
    int o = (int)(idx - (1u << 20));
    int c = o >> 9, r = o & 511;
    w1T[o] = f2b(w1[(size_t)r * 2048 + c]);
  } else {
    int o = (int)(idx - (2u << 20));
    int c = o >> 11, r = o & 2047;
    w2T[o] = f2b(w2[(size_t)r * 512 + c]);
  }
}

// ---------------- LayerNorm fp32 -> bf16, one wave per row (D=512) ----------------
__global__ __launch_bounds__(256) void ln_bf16(const float* __restrict__ x,
                                               const float* __restrict__ g,
                                               const float* __restrict__ bta,
                                               unsigned short* __restrict__ out) {
  const int t = threadIdx.x, l = t & 63, w = t >> 6;
  const size_t row = (size_t)blockIdx.x * 4 + w;
  const float4* xr = (const float4*)(x + row * ND);
  float4 a = xr[l];
  float4 bq = xr[64 + l];
  float s = a.x + a.y + a.z + a.w + bq.x + bq.y + bq.z + bq.w;
  float ss = a.x * a.x + a.y * a.y + a.z * a.z + a.w * a.w +
             bq.x * bq.x + bq.y * bq.y + bq.z * bq.z + bq.w * bq.w;
#pragma unroll
  for (int msk = 1; msk <= 32; msk <<= 1) {
    s += __shfl_xor(s, msk);
    ss += __shfl_xor(ss, msk);
  }
  float mu = s * (1.0f / ND);
  float var = ss * (1.0f / ND) - mu * mu;
  float rr = rsqrtf(var + 1e-6f);
  const float4* g4 = (const float4*)g;
  const float4* b4 = (const float4*)bta;
  float4 g0 = g4[l], g1 = g4[64 + l], b0 = b4[l], b1 = b4[64 + l];
  ushort4 o0, o1;
  o0.x = f2b((a.x - mu) * rr * g0.x + b0.x);
  o0.y = f2b((a.y - mu) * rr * g0.y + b0.y);
  o0.z = f2b((a.z - mu) * rr * g0.z + b0.z);
  o0.w = f2b((a.w - mu) * rr * g0.w + b0.w);
  o1.x = f2b((bq.x - mu) * rr * g1.x + b1.x);
  o1.y = f2b((bq.y - mu) * rr * g1.y + b1.y);
  o1.z = f2b((bq.z - mu) * rr * g1.z + b1.z);
  o1.w = f2b((bq.w - mu) * rr * g1.w + b1.w);
  ushort4* orow = (ushort4*)(out + row * ND);
  orow[l] = o0;
  orow[64 + l] = o1;
}

// ---------------- MFMA GEMM: C[M][N] = A[M][K] * Bt[N][K]^T ----------------
// 128x128 tile, BK=32, 4 waves. 2-phase double-buffered K-loop: stage(t+1)
// issued before compute(t); counted s_waitcnt vmcnt(4) + raw barriers (no full
// drain in steady state). Bijective XCD swizzle on the flat block id.
// EPI: 0 = QKV scatter (Q,K -> [B][H][S][HD]; V -> transposed [B][H][HD][S]);
//      1 = +inputs -> fp32 xres; 2 = gelu(+b1) -> bf16; 3 = +b2 +xres -> fp32.
template <int EPI>
__global__ __launch_bounds__(256) void gemm_bt(const unsigned short* __restrict__ A,
                                               const unsigned short* __restrict__ Bt,
                                               int M, int N, int K,
                                               unsigned short* __restrict__ ob,
                                               float* __restrict__ of,
                                               const float* __restrict__ addf,
                                               const float* __restrict__ bias) {
  __shared__ unsigned short lA[2][4096];
  __shared__ unsigned short lB[2][4096];
  const int t = threadIdx.x;
  const int l = t & 63, w = t >> 6;
  const int wr = w >> 1, wc = w & 1;
  const int gx = gridDim.x;
  const int nwg = gx * gridDim.y;
  const int fid = blockIdx.y * gx + blockIdx.x;
  const int q8 = nwg >> 3, r8 = nwg & 7, xcd = fid & 7, idx = fid >> 3;
  const int lid = (xcd < r8 ? xcd * (q8 + 1) : r8 * (q8 + 1) + (xcd - r8) * q8) + idx;
  const int bm = lid / gx, bn = lid % gx;
  const size_t rowBytes = (size_t)K * 2;
  const char* Ab = (const char*)A + (size_t)bm * 128 * rowBytes;
  const char* Bb = (const char*)Bt + (size_t)bn * 128 * rowBytes;
  const int o0 = t * 16, o1 = t * 16 + 4096;
  const int r0 = o0 >> 6, c0 = o0 & 63;
  const int r1 = o1 >> 6, c1 = o1 & 63;
  f32x4 acc[4][4] = {};

  auto stage = [&](int buf, int k0) {
    char* dA = (char*)lA + buf * 8192;
    char* dB = (char*)lB + buf * 8192;
    gload16(Ab + (size_t)r0 * rowBytes + 2 * k0 + c0, dA + o0);
    gload16(Ab + (size_t)r1 * rowBytes + 2 * k0 + c1, dA + o1);
    gload16(Bb + (size_t)r0 * rowBytes + 2 * k0 + c0, dB + o0);
    gload16(Bb + (size_t)r1 * rowBytes + 2 * k0 + c1, dB + o1);
  };

  stage(0, 0);
  int cur = 0;
  for (int k0 = 0; k0 < K; k0 += 32) {
    if (k0 + 32 < K) {
      stage(cur ^ 1, k0 + 32);
      asm volatile("s_waitcnt vmcnt(4)" ::: "memory");
    } else {
      asm volatile("s_waitcnt vmcnt(0)" ::: "memory");
    }
    __builtin_amdgcn_s_barrier();
    __builtin_amdgcn_sched_barrier(0);
    bf16x8 aF[4], bF[4];
#pragma unroll
    for (int m = 0; m < 4; ++m)
      aF[m] = *(const bf16x8*)&lA[cur][(wr * 64 + m * 16 + (l & 15)) * 32 + (l >> 4) * 8];
#pragma unroll
    for (int n = 0; n < 4; ++n)
      bF[n] = *(const bf16x8*)&lB[cur][(wc * 64 + n * 16 + (l & 15)) * 32 + (l >> 4) * 8];
#pragma unroll
    for (int m = 0; m < 4; ++m)
#pragma unroll
      for (int n = 0; n < 4; ++n)
        acc[m][n] = __builtin_amdgcn_mfma_f32_16x16x32_bf16(aF[m], bF[n], acc[m][n], 0, 0, 0);
    asm volatile("s_waitcnt lgkmcnt(0)" ::: "memory");
    __builtin_amdgcn_s_barrier();
    cur ^= 1;
  }
#pragma unroll
  for (int m = 0; m < 4; ++m)
#pragma unroll
    for (int n = 0; n < 4; ++n) {
      int row0 = bm * 128 + wr * 64 + m * 16 + (l >> 4) * 4;
      int col = bn * 128 + wc * 64 + n * 16 + (l & 15);
      if constexpr (EPI == 0) {
        int part = col >> 9, nn = col & 511;
        int hh = nn >> 6, hd = nn & 63;
        int b = row0 >> 12, sidx0 = row0 & 4095;
        if (part < 2) {
#pragma unroll
          for (int j = 0; j < 4; ++j)
            ob[((((size_t)part * NB + b) * NH + hh) * NS + sidx0 + j) * NHD + hd] =
                f2b(acc[m][n][j]);
        } else {
          ushort4 o;
          o.x = f2b(acc[m][n][0]);
          o.y = f2b(acc[m][n][1]);
          o.z = f2b(acc[m][n][2]);
          o.w = f2b(acc[m][n][3]);
          // V^T: [B][H][HD][S], appended after Q,K in the qkv buffer
          *(ushort4*)&ob[(((size_t)2 * NB) * NH * NS * NHD) +
                         (((size_t)b * NH + hh) * NHD + hd) * NS + sidx0 -
                         ((size_t)2 * NB) * NH * NS * NHD +
                         ((size_t)2 * NB) * NH * NS * NHD] = o;
        }
      } else {
#pragma unroll
        for (int j = 0; j < 4; ++j) {
          int row = row0 + j;
          float v = acc[m][n][j];
          if constexpr (EPI == 1) {
            size_t i = (size_t)row * ND + col;
            of[i] = v + addf[i];
          } else if constexpr (EPI == 2) {
            size_t i = (size_t)row * NMLP + col;
            ob[i] = f2b(geluf(v + bias[col]));
          } else if constexpr (EPI == 3) {
            size_t i = (size_t)row * ND + col;
            of[i] = v + bias[col] + addf[i];
          }
        }
      }
    }
}

// ---------------- block-sparse flash attention ----------------
// 8 waves x 16 q-rows, 128-key chunks. K staged [128][72] from [B][H][S][HD];
// V staged [64][136] directly from global V^T [B][H][HD][S] (vector b128 ops,
// conflict-free). Local block = one 128-key chunk computed triangularly
// (wave w: QK tiles n<=w, PV k-slices ks<=w/2). T14 reg-prefetch of next chunk.
__global__ __launch_bounds__(512, 4) void attn_sparse(const unsigned short* __restrict__ qm,
                                                      const unsigned short* __restrict__ km,
                                                      const unsigned short* __restrict__ vTg,
                                                      unsigned short* __restrict__ ctx) {
  __shared__ unsigned short kl[128 * 72];
  __shared__ unsigned short vt[64 * 136];
  __shared__ unsigned short pl[8][16 * 72];
  const int t = threadIdx.x, l = t & 63, w = t >> 6;
  const int bid = blockIdx.x;
  const int qbRaw = bid & 31, hh = (bid >> 5) & 7, b = bid >> 8;
  const int qb = b ? (31 - qbRaw) : qbRaw;  // work-complement pairing across batch
  const size_t bh = ((size_t)b * NH + hh) * NS;
  const size_t bhd = ((size_t)b * NH + hh) * NHD;
  const int qrow0 = qb * 128 + w * 16;
  bf16x8 qa[2];
#pragma unroll
  for (int ks = 0; ks < 2; ++ks)
    qa[ks] = *(const bf16x8*)&qm[(bh + qrow0 + (l & 15)) * NHD + ks * 32 + (l >> 4) * 8];
  f32x4 c[4] = {};
  float mrun[4], lrun[4];
#pragma unroll
  for (int j = 0; j < 4; ++j) { mrun[j] = -1e30f; lrun[j] = 0.0f; }

  const int nsum128 = qb >> 2, rem = qb & 3;
  const int nSumCh = nsum128 + (rem ? 1 : 0);
  const int nch = nSumCh + 1;
  const int kkey = t >> 2, kd = (t & 3) * 16;  // K staging: 4 threads per key row
  const int vd = t >> 3, vk = (t & 7) * 16;    // V staging: 8 threads per d row

  s16x8 kr0, kr1, vr0, vr1;
  auto issueLoads = [&](int c2) {
    int grK, sV;
    if (c2 < nSumCh) {
      grK = ((c2 << 2) + (kkey >> 5)) * 128 + 96 + (kkey & 31);
      sV = ((c2 << 2) + (vk >> 5)) * 128 + 96 + (vk & 31);
    } else {
      grK = qb * 128 + kkey;
      sV = qb * 128 + vk;
    }
    const unsigned short* kp = &km[(bh + grK) * NHD + kd];
    kr0 = *(const s16x8*)kp;
    kr1 = *(const s16x8*)(kp + 8);
    const unsigned short* vp = &vTg[(bhd + vd) * NS + sV];
    vr0 = *(const s16x8*)vp;
    vr1 = *(const s16x8*)(vp + 8);
  };

  issueLoads(0);
  for (int ch = 0; ch < nch; ++ch) {
    if (ch) {  // all waves done reading previous chunk's LDS
      asm volatile("s_waitcnt lgkmcnt(0)" ::: "memory");
      __builtin_amdgcn_s_barrier();
    }
    *(s16x8*)&kl[kkey * 72 + kd] = kr0;
    *(s16x8*)&kl[kkey * 72 + kd + 8] = kr1;
    *(s16x8*)&vt[vd * 136 + vk] = vr0;
    *(s16x8*)&vt[vd * 136 + vk + 8] = vr1;
    asm volatile("s_waitcnt lgkmcnt(0)" ::: "memory");
    __builtin_amdgcn_s_barrier();
    __builtin_amdgcn_sched_barrier(0);
    if (ch + 1 < nch) issueLoads(ch + 1);  // in flight during compute

    const bool isLocal = (ch == nch - 1);
    const bool isRem = (rem != 0) && !isLocal && (ch == nsum128);
    const int nT = isLocal ? (w + 1) : (isRem ? 2 * rem : 8);
    const int nTpl = isLocal ? ((w | 1) + 1) : nT;  // even; PV reads pairs
    const int nKs = nTpl >> 1;

    f32x4 sf[8];
#pragma unroll
    for (int n = 0; n < 8; ++n) {
      if (n < nT) {
        const bf16x8 k0 = *(const bf16x8*)&kl[(n * 16 + (l & 15)) * 72 + (l >> 4) * 8];
        const bf16x8 k1 = *(const bf16x8*)&kl[(n * 16 + (l & 15)) * 72 + 32 + (l >> 4) * 8];
        f32x4 a = {};
        a = __builtin_amdgcn_mfma_f32_16x16x32_bf16(qa[0], k0, a, 0, 0, 0);
        a = __builtin_amdgcn_mfma_f32_16x16x32_bf16(qa[1], k1, a, 0, 0, 0);
        if (isLocal && n == w) {  // diagonal tile: triangular mask
#pragma unroll
          for (int j = 0; j < 4; ++j)
            if ((l & 15) > (l >> 4) * 4 + j) a[j] = -1e9f;
        }
        sf[n] = a;
      }
    }
    // online softmax
    float cm[4], al[4];
#pragma unroll
    for (int j = 0; j < 4; ++j) cm[j] = -1e30f;
#pragma unroll
    for (int n = 0; n < 8; ++n)
      if (n < nT)
#pragma unroll
        for (int j = 0; j < 4; ++j) cm[j] = fmaxf(cm[j], sf[n][j]);
#pragma unroll
    for (int j = 0; j < 4; ++j) {
      cm[j] = fmaxf(cm[j], __shfl_xor(cm[j], 1));
      cm[j] = fmaxf(cm[j], __shfl_xor(cm[j], 2));
      cm[j] = fmaxf(cm[j], __shfl_xor(cm[j], 4));
      cm[j] = fmaxf(cm[j], __shfl_xor(cm[j], 8));
      float nm = fmaxf(mrun[j], cm[j]);
      al[j] = __expf(mrun[j] - nm);
      mrun[j] = nm;
    }
#pragma unroll
    for (int n = 0; n < 4; ++n)
#pragma unroll
      for (int j = 0; j < 4; ++j) c[n][j] *= al[j];
    float rs[4] = {0.f, 0.f, 0.f, 0.f};
#pragma unroll
    for (int n = 0; n < 8; ++n)
      if (n < nT)
#pragma unroll
        for (int j = 0; j < 4; ++j) {
          float p = __expf(sf[n][j] - mrun[j]);
          sf[n][j] = p;
          rs[j] += p;
        }
#pragma unroll
    for (int j = 0; j < 4; ++j) {
      rs[j] += __shfl_xor(rs[j], 1);
      rs[j] += __shfl_xor(rs[j], 2);
      rs[j] += __shfl_xor(rs[j], 4);
      rs[j] += __shfl_xor(rs[j], 8);
      lrun[j] = lrun[j] * al[j] + rs[j];
    }
    // PV in two 64-key halves through per-wave LDS (same-wave, no barrier)
#pragma unroll
    for (int h = 0; h < 2; ++h) {
      if (h * 4 < nTpl) {
#pragma unroll
        for (int n2 = 0; n2 < 4; ++n2) {
          const int n = h * 4 + n2;
#pragma unroll
          for (int j = 0; j < 4; ++j) {
            if (n < nTpl) {
              unsigned short pv = 0;
              if (n < nT) pv = f2b(sf[n][j]);
              pl[w][((l >> 4) * 4 + j) * 72 + n2 * 16 + (l & 15)] = pv;
            }
          }
        }
#pragma unroll
        for (int ks2 = 0; ks2 < 2; ++ks2) {
          const int ks = h * 2 + ks2;
          if (ks < nKs) {
            const bf16x8 pa = *(const bf16x8*)&pl[w][(l & 15) * 72 + ks2 * 32 + (l >> 4) * 8];
#pragma unroll
            for (int nd = 0; nd < 4; ++nd) {
              const bf16x8 vb =
                  *(const bf16x8*)&vt[(nd * 16 + (l & 15)) * 136 + ks * 32 + (l >> 4) * 8];
              c[nd] = __builtin_amdgcn_mfma_f32_16x16x32_bf16(pa, vb, c[nd], 0, 0, 0);
            }
          }
        }
      }
    }
  }
  // write ctx as [B][S][H*HD] bf16
#pragma unroll
  for (int n = 0; n < 4; ++n)
#pragma unroll
    for (int j = 0; j < 4; ++j) {
      int srow = qrow0 + (l >> 4) * 4 + j;
      int col = n * 16 + (l & 15);
      ctx[((size_t)b * NS + srow) * ND + hh * NHD + col] = f2b(c[n][j] / lrun[j]);
    }
}

extern "C" void kernel_launch(void* const* d_in, const int* in_sizes, int n_in,
                              void* d_out, int out_size, void* d_ws, size_t ws_size,
                              hipStream_t stream) {
  (void)in_sizes; (void)n_in; (void)out_size; (void)ws_size;
  const float* inputs = (const float*)d_in[0];
  const float* ln1s = (const float*)d_in[1];
  const float* ln1b = (const float*)d_in[2];
  const float* wq = (const float*)d_in[3];
  const float* wk = (const float*)d_in[4];
  const float* wv = (const float*)d_in[5];
  const float* wo = (const float*)d_in[6];
  const float* ln2s = (const float*)d_in[7];
  const float* ln2b = (const float*)d_in[8];
  const float* w1 = (const float*)d_in[9];
  const float* b1 = (const float*)d_in[10];
  const float* w2 = (const float*)d_in[11];
  const float* b2 = (const float*)d_in[12];
  float* out = (float*)d_out;

  // workspace layout (~102 MB)
  unsigned short* xln = (unsigned short*)d_ws;                 // 8192*512 bf16
  unsigned short* xln2 = xln + (size_t)8192 * 512;             // 8192*512
  unsigned short* ctx = xln2 + (size_t)8192 * 512;             // 8192*512
  unsigned short* qkv = ctx + (size_t)8192 * 512;              // 3 * 8192*512 (Q, K, V^T)
  float* xres = (float*)(qkv + (size_t)3 * 8192 * 512);        // 8192*512 fp32
  unsigned short* hbuf = (unsigned short*)(xres + (size_t)8192 * 512);  // 8192*2048
  unsigned short* qkvT = hbuf + (size_t)8192 * 2048;           // 1536*512
  unsigned short* woT = qkvT + (size_t)1536 * 512;             // 512*512
  unsigned short* w1T = woT + (size_t)512 * 512;               // 2048*512
  unsigned short* w2T = w1T + (size_t)2048 * 512;              // 512*2048

  prep_weights<<<12288, 256, 0, stream>>>(wq, wk, wv, wo, w1, w2, qkvT, woT, w1T, w2T);
  ln_bf16<<<2048, 256, 0, stream>>>(inputs, ln1s, ln1b, xln);
  gemm_bt<0><<<dim3(12, 64), 256, 0, stream>>>(xln, qkvT, 8192, 1536, 512,
                                               qkv, nullptr, nullptr, nullptr);
  attn_sparse<<<512, 512, 0, stream>>>(qkv, qkv + (size_t)8192 * 512,
                                       qkv + (size_t)2 * 8192 * 512, ctx);
  gemm_bt<1><<<dim3(4, 64), 256, 0, stream>>>(ctx, woT, 8192, 512, 512,
                                              nullptr, xres, inputs, nullptr);
  ln_bf16<<<2048, 256, 0, stream>>>(xres, ln2s, ln2b, xln2);
  gemm_bt<2><<<dim3(16, 64), 256, 0, stream>>>(xln2, w1T, 8192, 2048, 512,
                                               hbuf, nullptr, nullptr, b1);
  gemm_bt<3><<<dim3(4, 64), 256, 0, stream>>>(hbuf, w2T, 8192, 512, 2048,
                                              nullptr, out, xres, b2);
}

// Round 5
// 180.678 us; speedup vs baseline: 1.5447x; 1.0364x over previous
//
#include <hip/hip_runtime.h>
#include <hip/hip_bf16.h>

typedef __attribute__((ext_vector_type(8))) __bf16 bf16x8;
typedef __attribute__((ext_vector_type(8))) short s16x8;
typedef __attribute__((ext_vector_type(4))) float f32x4;

#define NB 2
#define NS 4096
#define ND 512
#define NH 8
#define NHD 64
#define NMLP 2048

__device__ __forceinline__ unsigned short f2b(float f) {
  __hip_bfloat16 h = __float2bfloat16(f);
  return __builtin_bit_cast(unsigned short, h);
}

__device__ __forceinline__ float geluf(float x) {
  return 0.5f * x * (1.0f + tanhf(0.7978845608028654f * (x + 0.044715f * x * x * x)));
}

__device__ __forceinline__ void gload16(const void* g, void* l) {
  __builtin_amdgcn_global_load_lds((const __attribute__((address_space(1))) void*)g,
                                   (__attribute__((address_space(3))) void*)l, 16, 0, 0);
}

// ---------------- weight transposes: 64x64 LDS-tiled, one launch ----------------
__global__ __launch_bounds__(256) void prep_weights(const float* __restrict__ wq,
                                                    const float* __restrict__ wk,
                                                    const float* __restrict__ wv,
                                                    const float* __restrict__ wo,
                                                    const float* __restrict__ w1,
                                                    const float* __restrict__ w2,
                                                    unsigned short* __restrict__ qkvT,
                                                    unsigned short* __restrict__ woT,
                                                    unsigned short* __restrict__ w1T,
                                                    unsigned short* __restrict__ w2T) {
  __shared__ unsigned short lt[64][66];
  const int tile = blockIdx.x, t = threadIdx.x;
  const float* src;
  unsigned short* dst;
  int R, C, tr, tc;
  float sc = 1.0f;
  if (tile < 256) {
    int seg = tile >> 6, tt = tile & 63;
    R = 512; C = 512;
    src = seg == 0 ? wq : seg == 1 ? wk : seg == 2 ? wv : wo;
    dst = (seg < 3) ? (qkvT + ((size_t)seg << 18)) : woT;
    if (seg == 0) sc = 0.125f;
    tr = tt >> 3; tc = tt & 7;
  } else if (tile < 512) {
    int tt = tile - 256;
    R = 512; C = 2048; src = w1; dst = w1T;
    tr = tt >> 5; tc = tt & 31;
  } else {
    int tt = tile - 512;
    R = 2048; C = 512; src = w2; dst = w2T;
    tr = tt >> 3; tc = tt & 7;
  }
  const int r0 = tr * 64, c0 = tc * 64;
  const int fx = t & 15, fy = t >> 4;
#pragma unroll
  for (int p = 0; p < 4; ++p) {
    int rr = p * 16 + fy;
    float4 v = *(const float4*)&src[(size_t)(r0 + rr) * C + c0 + fx * 4];
    lt[rr][fx * 4 + 0] = f2b(v.x * sc);
    lt[rr][fx * 4 + 1] = f2b(v.y * sc);
    lt[rr][fx * 4 + 2] = f2b(v.z * sc);
    lt[rr][fx * 4 + 3] = f2b(v.w * sc);
  }
  __syncthreads();
#pragma unroll
  for (int p = 0; p < 4; ++p) {
    int cc = p * 16 + fy;
    ushort4 o;
    o.x = lt[fx * 4 + 0][cc];
    o.y = lt[fx * 4 + 1][cc];
    o.z = lt[fx * 4 + 2][cc];
    o.w = lt[fx * 4 + 3][cc];
    *(ushort4*)&dst[(size_t)(c0 + cc) * R + r0 + fx * 4] = o;
  }
}

// ---------------- LayerNorm fp32 -> bf16, one wave per row (D=512) ----------------
__global__ __launch_bounds__(256) void ln_bf16(const float* __restrict__ x,
                                               const float* __restrict__ g,
                                               const float* __restrict__ bta,
                                               unsigned short* __restrict__ out) {
  const int t = threadIdx.x, l = t & 63, w = t >> 6;
  const size_t row = (size_t)blockIdx.x * 4 + w;
  const float4* xr = (const float4*)(x + row * ND);
  float4 a = xr[l];
  float4 bq = xr[64 + l];
  float s = a.x + a.y + a.z + a.w + bq.x + bq.y + bq.z + bq.w;
  float ss = a.x * a.x + a.y * a.y + a.z * a.z + a.w * a.w +
             bq.x * bq.x + bq.y * bq.y + bq.z * bq.z + bq.w * bq.w;
#pragma unroll
  for (int msk = 1; msk <= 32; msk <<= 1) {
    s += __shfl_xor(s, msk);
    ss += __shfl_xor(ss, msk);
  }
  float mu = s * (1.0f / ND);
  float var = ss * (1.0f / ND) - mu * mu;
  float rr = rsqrtf(var + 1e-6f);
  const float4* g4 = (const float4*)g;
  const float4* b4 = (const float4*)bta;
  float4 g0 = g4[l], g1 = g4[64 + l], b0 = b4[l], b1 = b4[64 + l];
  ushort4 o0, o1;
  o0.x = f2b((a.x - mu) * rr * g0.x + b0.x);
  o0.y = f2b((a.y - mu) * rr * g0.y + b0.y);
  o0.z = f2b((a.z - mu) * rr * g0.z + b0.z);
  o0.w = f2b((a.w - mu) * rr * g0.w + b0.w);
  o1.x = f2b((bq.x - mu) * rr * g1.x + b1.x);
  o1.y = f2b((bq.y - mu) * rr * g1.y + b1.y);
  o1.z = f2b((bq.z - mu) * rr * g1.z + b1.z);
  o1.w = f2b((bq.w - mu) * rr * g1.w + b1.w);
  ushort4* orow = (ushort4*)(out + row * ND);
  orow[l] = o0;
  orow[64 + l] = o1;
}

// ---------------- MFMA GEMM: C[M][N] = A[M][K] * Bt[N][K]^T ----------------
// 128x128 tile, BK=32, 4 waves. 3-deep gload_lds pipeline: prologue stages
// tiles 0,1; loop stages t+2 then waits vmcnt(8) (tile t ready, t+1/t+2 in
// flight). Buffer staged at iter t == buffer drained at end of iter t-1.
// Bijective XCD swizzle; setprio around the MFMA cluster.
template <int EPI>
__global__ __launch_bounds__(256) void gemm_bt(const unsigned short* __restrict__ A,
                                               const unsigned short* __restrict__ Bt,
                                               int M, int N, int K,
                                               unsigned short* __restrict__ ob,
                                               float* __restrict__ of,
                                               const float* __restrict__ addf,
                                               const float* __restrict__ bias) {
  __shared__ unsigned short lA[3][4096];
  __shared__ unsigned short lB[3][4096];
  const int t = threadIdx.x;
  const int l = t & 63, w = t >> 6;
  const int wr = w >> 1, wc = w & 1;
  const int gx = gridDim.x;
  const int nwg = gx * gridDim.y;
  const int fid = blockIdx.y * gx + blockIdx.x;
  const int q8 = nwg >> 3, r8 = nwg & 7, xcd = fid & 7, idx = fid >> 3;
  const int lid = (xcd < r8 ? xcd * (q8 + 1) : r8 * (q8 + 1) + (xcd - r8) * q8) + idx;
  const int bm = lid / gx, bn = lid % gx;
  const size_t rowBytes = (size_t)K * 2;
  const char* Ab = (const char*)A + (size_t)bm * 128 * rowBytes;
  const char* Bb = (const char*)Bt + (size_t)bn * 128 * rowBytes;
  const int o0 = t * 16, o1 = t * 16 + 4096;
  const int r0 = o0 >> 6, c0 = o0 & 63;
  const int r1 = o1 >> 6, c1 = o1 & 63;
  f32x4 acc[4][4] = {};

  auto stage = [&](int buf, int k0) {
    char* dA = (char*)&lA[buf][0];
    char* dB = (char*)&lB[buf][0];
    gload16(Ab + (size_t)r0 * rowBytes + 2 * k0 + c0, dA + o0);
    gload16(Ab + (size_t)r1 * rowBytes + 2 * k0 + c1, dA + o1);
    gload16(Bb + (size_t)r0 * rowBytes + 2 * k0 + c0, dB + o0);
    gload16(Bb + (size_t)r1 * rowBytes + 2 * k0 + c1, dB + o1);
  };

  stage(0, 0);
  if (32 < K) stage(1, 32);
  int cur = 0;
  for (int k0 = 0; k0 < K; k0 += 32) {
    int nb1 = cur + 1; if (nb1 == 3) nb1 = 0;
    int nb2 = nb1 + 1; if (nb2 == 3) nb2 = 0;
    if (k0 + 64 < K) {
      stage(nb2, k0 + 64);
      asm volatile("s_waitcnt vmcnt(8)" ::: "memory");
    } else if (k0 + 32 < K) {
      asm volatile("s_waitcnt vmcnt(4)" ::: "memory");
    } else {
      asm volatile("s_waitcnt vmcnt(0)" ::: "memory");
    }
    __builtin_amdgcn_s_barrier();
    __builtin_amdgcn_sched_barrier(0);
    bf16x8 aF[4], bF[4];
#pragma unroll
    for (int m = 0; m < 4; ++m)
      aF[m] = *(const bf16x8*)&lA[cur][(wr * 64 + m * 16 + (l & 15)) * 32 + (l >> 4) * 8];
#pragma unroll
    for (int n = 0; n < 4; ++n)
      bF[n] = *(const bf16x8*)&lB[cur][(wc * 64 + n * 16 + (l & 15)) * 32 + (l >> 4) * 8];
    __builtin_amdgcn_s_setprio(1);
#pragma unroll
    for (int m = 0; m < 4; ++m)
#pragma unroll
      for (int n = 0; n < 4; ++n)
        acc[m][n] = __builtin_amdgcn_mfma_f32_16x16x32_bf16(aF[m], bF[n], acc[m][n], 0, 0, 0);
    __builtin_amdgcn_s_setprio(0);
    asm volatile("s_waitcnt lgkmcnt(0)" ::: "memory");
    __builtin_amdgcn_s_barrier();
    cur = nb1;
  }
#pragma unroll
  for (int m = 0; m < 4; ++m)
#pragma unroll
    for (int n = 0; n < 4; ++n) {
      int row0 = bm * 128 + wr * 64 + m * 16 + (l >> 4) * 4;
      int col = bn * 128 + wc * 64 + n * 16 + (l & 15);
      if constexpr (EPI == 0) {
        int part = col >> 9, nn = col & 511;
        int hh = nn >> 6, hd = nn & 63;
        int b = row0 >> 12, sidx0 = row0 & 4095;
        if (part < 2) {
#pragma unroll
          for (int j = 0; j < 4; ++j)
            ob[((((size_t)part * NB + b) * NH + hh) * NS + sidx0 + j) * NHD + hd] =
                f2b(acc[m][n][j]);
        } else {
          ushort4 o;
          o.x = f2b(acc[m][n][0]);
          o.y = f2b(acc[m][n][1]);
          o.z = f2b(acc[m][n][2]);
          o.w = f2b(acc[m][n][3]);
          // V^T: [B][H][HD][S], third segment of the qkv buffer
          *(ushort4*)&ob[(size_t)2 * NB * NH * NS * NHD +
                         (((size_t)b * NH + hh) * NHD + hd) * NS + sidx0] = o;
        }
      } else {
#pragma unroll
        for (int j = 0; j < 4; ++j) {
          int row = row0 + j;
          float v = acc[m][n][j];
          if constexpr (EPI == 1) {
            size_t i = (size_t)row * ND + col;
            of[i] = v + addf[i];
          } else if constexpr (EPI == 2) {
            size_t i = (size_t)row * NMLP + col;
            ob[i] = f2b(geluf(v + bias[col]));
          } else if constexpr (EPI == 3) {
            size_t i = (size_t)row * ND + col;
            of[i] = v + bias[col] + addf[i];
          }
        }
      }
    }
}

// ---------------- block-sparse flash attention ----------------
// 8 waves x 16 q-rows, 128-key chunks. K staged [128][72] from [B][H][S][HD];
// V staged [64][136] from global V^T [B][H][HD][S] (vector ops, conflict-free).
// Local block computed triangularly; reg-prefetch of next chunk under compute.
__global__ __launch_bounds__(512, 4) void attn_sparse(const unsigned short* __restrict__ qm,
                                                      const unsigned short* __restrict__ km,
                                                      const unsigned short* __restrict__ vTg,
                                                      unsigned short* __restrict__ ctx) {
  __shared__ unsigned short kl[128 * 72];
  __shared__ unsigned short vt[64 * 136];
  __shared__ unsigned short pl[8][16 * 72];
  const int t = threadIdx.x, l = t & 63, w = t >> 6;
  const int bid = blockIdx.x;
  const int qbRaw = bid & 31, hh = (bid >> 5) & 7, b = bid >> 8;
  const int qb = b ? (31 - qbRaw) : qbRaw;  // work-complement pairing across batch
  const size_t bh = ((size_t)b * NH + hh) * NS;
  const size_t bhd = ((size_t)b * NH + hh) * NHD;
  const int qrow0 = qb * 128 + w * 16;
  bf16x8 qa[2];
#pragma unroll
  for (int ks = 0; ks < 2; ++ks)
    qa[ks] = *(const bf16x8*)&qm[(bh + qrow0 + (l & 15)) * NHD + ks * 32 + (l >> 4) * 8];
  f32x4 c[4] = {};
  float mrun[4], lrun[4];
#pragma unroll
  for (int j = 0; j < 4; ++j) { mrun[j] = -1e30f; lrun[j] = 0.0f; }

  const int nsum128 = qb >> 2, rem = qb & 3;
  const int nSumCh = nsum128 + (rem ? 1 : 0);
  const int nch = nSumCh + 1;
  const int kkey = t >> 2, kd = (t & 3) * 16;
  const int vd = t >> 3, vk = (t & 7) * 16;

  s16x8 kr0, kr1, vr0, vr1;
  auto issueLoads = [&](int c2) {
    int grK, sV;
    if (c2 < nSumCh) {
      grK = ((c2 << 2) + (kkey >> 5)) * 128 + 96 + (kkey & 31);
      sV = ((c2 << 2) + (vk >> 5)) * 128 + 96 + (vk & 31);
    } else {
      grK = qb * 128 + kkey;
      sV = qb * 128 + vk;
    }
    const unsigned short* kp = &km[(bh + grK) * NHD + kd];
    kr0 = *(const s16x8*)kp;
    kr1 = *(const s16x8*)(kp + 8);
    const unsigned short* vp = &vTg[(bhd + vd) * NS + sV];
    vr0 = *(const s16x8*)vp;
    vr1 = *(const s16x8*)(vp + 8);
  };

  issueLoads(0);
  for (int ch = 0; ch < nch; ++ch) {
    if (ch) {
      asm volatile("s_waitcnt lgkmcnt(0)" ::: "memory");
      __builtin_amdgcn_s_barrier();
    }
    *(s16x8*)&kl[kkey * 72 + kd] = kr0;
    *(s16x8*)&kl[kkey * 72 + kd + 8] = kr1;
    *(s16x8*)&vt[vd * 136 + vk] = vr0;
    *(s16x8*)&vt[vd * 136 + vk + 8] = vr1;
    asm volatile("s_waitcnt lgkmcnt(0)" ::: "memory");
    __builtin_amdgcn_s_barrier();
    __builtin_amdgcn_sched_barrier(0);
    if (ch + 1 < nch) issueLoads(ch + 1);

    const bool isLocal = (ch == nch - 1);
    const bool isRem = (rem != 0) && !isLocal && (ch == nsum128);
    const int nT = isLocal ? (w + 1) : (isRem ? 2 * rem : 8);
    const int nTpl = isLocal ? ((w | 1) + 1) : nT;
    const int nKs = nTpl >> 1;

    f32x4 sf[8];
#pragma unroll
    for (int n = 0; n < 8; ++n) {
      if (n < nT) {
        const bf16x8 k0 = *(const bf16x8*)&kl[(n * 16 + (l & 15)) * 72 + (l >> 4) * 8];
        const bf16x8 k1 = *(const bf16x8*)&kl[(n * 16 + (l & 15)) * 72 + 32 + (l >> 4) * 8];
        f32x4 a = {};
        a = __builtin_amdgcn_mfma_f32_16x16x32_bf16(qa[0], k0, a, 0, 0, 0);
        a = __builtin_amdgcn_mfma_f32_16x16x32_bf16(qa[1], k1, a, 0, 0, 0);
        if (isLocal && n == w) {
#pragma unroll
          for (int j = 0; j < 4; ++j)
            if ((l & 15) > (l >> 4) * 4 + j) a[j] = -1e9f;
        }
        sf[n] = a;
      }
    }
    float cm[4], al[4];
#pragma unroll
    for (int j = 0; j < 4; ++j) cm[j] = -1e30f;
#pragma unroll
    for (int n = 0; n < 8; ++n)
      if (n < nT)
#pragma unroll
        for (int j = 0; j < 4; ++j) cm[j] = fmaxf(cm[j], sf[n][j]);
#pragma unroll
    for (int j = 0; j < 4; ++j) {
      cm[j] = fmaxf(cm[j], __shfl_xor(cm[j], 1));
      cm[j] = fmaxf(cm[j], __shfl_xor(cm[j], 2));
      cm[j] = fmaxf(cm[j], __shfl_xor(cm[j], 4));
      cm[j] = fmaxf(cm[j], __shfl_xor(cm[j], 8));
      float nm = fmaxf(mrun[j], cm[j]);
      al[j] = __expf(mrun[j] - nm);
      mrun[j] = nm;
    }
#pragma unroll
    for (int n = 0; n < 4; ++n)
#pragma unroll
      for (int j = 0; j < 4; ++j) c[n][j] *= al[j];
    float rs[4] = {0.f, 0.f, 0.f, 0.f};
#pragma unroll
    for (int n = 0; n < 8; ++n)
      if (n < nT)
#pragma unroll
        for (int j = 0; j < 4; ++j) {
          float p = __expf(sf[n][j] - mrun[j]);
          sf[n][j] = p;
          rs[j] += p;
        }
#pragma unroll
    for (int j = 0; j < 4; ++j) {
      rs[j] += __shfl_xor(rs[j], 1);
      rs[j] += __shfl_xor(rs[j], 2);
      rs[j] += __shfl_xor(rs[j], 4);
      rs[j] += __shfl_xor(rs[j], 8);
      lrun[j] = lrun[j] * al[j] + rs[j];
    }
#pragma unroll
    for (int h = 0; h < 2; ++h) {
      if (h * 4 < nTpl) {
#pragma unroll
        for (int n2 = 0; n2 < 4; ++n2) {
          const int n = h * 4 + n2;
#pragma unroll
          for (int j = 0; j < 4; ++j) {
            if (n < nTpl) {
              unsigned short pv = 0;
              if (n < nT) pv = f2b(sf[n][j]);
              pl[w][((l >> 4) * 4 + j) * 72 + n2 * 16 + (l & 15)] = pv;
            }
          }
        }
#pragma unroll
        for (int ks2 = 0; ks2 < 2; ++ks2) {
          const int ks = h * 2 + ks2;
          if (ks < nKs) {
            const bf16x8 pa = *(const bf16x8*)&pl[w][(l & 15) * 72 + ks2 * 32 + (l >> 4) * 8];
#pragma unroll
            for (int nd = 0; nd < 4; ++nd) {
              const bf16x8 vb =
                  *(const bf16x8*)&vt[(nd * 16 + (l & 15)) * 136 + ks * 32 + (l >> 4) * 8];
              c[nd] = __builtin_amdgcn_mfma_f32_16x16x32_bf16(pa, vb, c[nd], 0, 0, 0);
            }
          }
        }
      }
    }
  }
#pragma unroll
  for (int n = 0; n < 4; ++n)
#pragma unroll
    for (int j = 0; j < 4; ++j) {
      int srow = qrow0 + (l >> 4) * 4 + j;
      int col = n * 16 + (l & 15);
      ctx[((size_t)b * NS + srow) * ND + hh * NHD + col] = f2b(c[n][j] / lrun[j]);
    }
}

extern "C" void kernel_launch(void* const* d_in, const int* in_sizes, int n_in,
                              void* d_out, int out_size, void* d_ws, size_t ws_size,
                              hipStream_t stream) {
  (void)in_sizes; (void)n_in; (void)out_size; (void)ws_size;
  const float* inputs = (const float*)d_in[0];
  const float* ln1s = (const float*)d_in[1];
  const float* ln1b = (const float*)d_in[2];
  const float* wq = (const float*)d_in[3];
  const float* wk = (const float*)d_in[4];
  const float* wv = (const float*)d_in[5];
  const float* wo = (const float*)d_in[6];
  const float* ln2s = (const float*)d_in[7];
  const float* ln2b = (const float*)d_in[8];
  const float* w1 = (const float*)d_in[9];
  const float* b1 = (const float*)d_in[10];
  const float* w2 = (const float*)d_in[11];
  const float* b2 = (const float*)d_in[12];
  float* out = (float*)d_out;

  // workspace layout (~102 MB)
  unsigned short* xln = (unsigned short*)d_ws;                 // 8192*512 bf16
  unsigned short* xln2 = xln + (size_t)8192 * 512;             // 8192*512
  unsigned short* ctx = xln2 + (size_t)8192 * 512;             // 8192*512
  unsigned short* qkv = ctx + (size_t)8192 * 512;              // 3 * 8192*512 (Q, K, V^T)
  float* xres = (float*)(qkv + (size_t)3 * 8192 * 512);        // 8192*512 fp32
  unsigned short* hbuf = (unsigned short*)(xres + (size_t)8192 * 512);  // 8192*2048
  unsigned short* qkvT = hbuf + (size_t)8192 * 2048;           // 1536*512
  unsigned short* woT = qkvT + (size_t)1536 * 512;             // 512*512
  unsigned short* w1T = woT + (size_t)512 * 512;               // 2048*512
  unsigned short* w2T = w1T + (size_t)2048 * 512;              // 512*2048

  prep_weights<<<768, 256, 0, stream>>>(wq, wk, wv, wo, w1, w2, qkvT, woT, w1T, w2T);
  ln_bf16<<<2048, 256, 0, stream>>>(inputs, ln1s, ln1b, xln);
  gemm_bt<0><<<dim3(12, 64), 256, 0, stream>>>(xln, qkvT, 8192, 1536, 512,
                                               qkv, nullptr, nullptr, nullptr);
  attn_sparse<<<512, 512, 0, stream>>>(qkv, qkv + (size_t)8192 * 512,
                                       qkv + (size_t)2 * 8192 * 512, ctx);
  gemm_bt<1><<<dim3(4, 64), 256, 0, stream>>>(ctx, woT, 8192, 512, 512,
                                              nullptr, xres, inputs, nullptr);
  ln_bf16<<<2048, 256, 0, stream>>>(xres, ln2s, ln2b, xln2);
  gemm_bt<2><<<dim3(16, 64), 256, 0, stream>>>(xln2, w1T, 8192, 2048, 512,
                                               hbuf, nullptr, nullptr, b1);
  gemm_bt<3><<<dim3(4, 64), 256, 0, stream>>>(hbuf, w2T, 8192, 512, 2048,
                                              nullptr, out, xres, b2);
}

// Round 6
// 172.275 us; speedup vs baseline: 1.6200x; 1.0488x over previous
//
#include <hip/hip_runtime.h>
#include <hip/hip_bf16.h>

typedef __attribute__((ext_vector_type(8))) __bf16 bf16x8;
typedef __attribute__((ext_vector_type(8))) short s16x8;
typedef __attribute__((ext_vector_type(4))) float f32x4;

#define NB 2
#define NS 4096
#define ND 512
#define NH 8
#define NHD 64
#define NMLP 2048

__device__ __forceinline__ unsigned short f2b(float f) {
  __hip_bfloat16 h = __float2bfloat16(f);
  return __builtin_bit_cast(unsigned short, h);
}

__device__ __forceinline__ float geluf(float x) {
  return 0.5f * x * (1.0f + tanhf(0.7978845608028654f * (x + 0.044715f * x * x * x)));
}

__device__ __forceinline__ void gload16(const void* g, void* l) {
  __builtin_amdgcn_global_load_lds((const __attribute__((address_space(1))) void*)g,
                                   (__attribute__((address_space(3))) void*)l, 16, 0, 0);
}

// ---------------- weight transposes: 64x64 LDS-tiled, one launch ----------------
__global__ __launch_bounds__(256) void prep_weights(const float* __restrict__ wq,
                                                    const float* __restrict__ wk,
                                                    const float* __restrict__ wv,
                                                    const float* __restrict__ wo,
                                                    const float* __restrict__ w1,
                                                    const float* __restrict__ w2,
                                                    unsigned short* __restrict__ qkvT,
                                                    unsigned short* __restrict__ woT,
                                                    unsigned short* __restrict__ w1T,
                                                    unsigned short* __restrict__ w2T) {
  __shared__ unsigned short lt[64][66];
  const int tile = blockIdx.x, t = threadIdx.x;
  const float* src;
  unsigned short* dst;
  int R, C, tr, tc;
  float sc = 1.0f;
  if (tile < 256) {
    int seg = tile >> 6, tt = tile & 63;
    R = 512; C = 512;
    src = seg == 0 ? wq : seg == 1 ? wk : seg == 2 ? wv : wo;
    dst = (seg < 3) ? (qkvT + ((size_t)seg << 18)) : woT;
    if (seg == 0) sc = 0.125f;
    tr = tt >> 3; tc = tt & 7;
  } else if (tile < 512) {
    int tt = tile - 256;
    R = 512; C = 2048; src = w1; dst = w1T;
    tr = tt >> 5; tc = tt & 31;
  } else {
    int tt = tile - 512;
    R = 2048; C = 512; src = w2; dst = w2T;
    tr = tt >> 3; tc = tt & 7;
  }
  const int r0 = tr * 64, c0 = tc * 64;
  const int fx = t & 15, fy = t >> 4;
#pragma unroll
  for (int p = 0; p < 4; ++p) {
    int rr = p * 16 + fy;
    float4 v = *(const float4*)&src[(size_t)(r0 + rr) * C + c0 + fx * 4];
    lt[rr][fx * 4 + 0] = f2b(v.x * sc);
    lt[rr][fx * 4 + 1] = f2b(v.y * sc);
    lt[rr][fx * 4 + 2] = f2b(v.z * sc);
    lt[rr][fx * 4 + 3] = f2b(v.w * sc);
  }
  __syncthreads();
#pragma unroll
  for (int p = 0; p < 4; ++p) {
    int cc = p * 16 + fy;
    ushort4 o;
    o.x = lt[fx * 4 + 0][cc];
    o.y = lt[fx * 4 + 1][cc];
    o.z = lt[fx * 4 + 2][cc];
    o.w = lt[fx * 4 + 3][cc];
    *(ushort4*)&dst[(size_t)(c0 + cc) * R + r0 + fx * 4] = o;
  }
}

// ---------------- LayerNorm fp32 -> bf16, one wave per row (D=512) ----------------
__global__ __launch_bounds__(256) void ln_bf16(const float* __restrict__ x,
                                               const float* __restrict__ g,
                                               const float* __restrict__ bta,
                                               unsigned short* __restrict__ out) {
  const int t = threadIdx.x, l = t & 63, w = t >> 6;
  const size_t row = (size_t)blockIdx.x * 4 + w;
  const float4* xr = (const float4*)(x + row * ND);
  float4 a = xr[l];
  float4 bq = xr[64 + l];
  float s = a.x + a.y + a.z + a.w + bq.x + bq.y + bq.z + bq.w;
  float ss = a.x * a.x + a.y * a.y + a.z * a.z + a.w * a.w +
             bq.x * bq.x + bq.y * bq.y + bq.z * bq.z + bq.w * bq.w;
#pragma unroll
  for (int msk = 1; msk <= 32; msk <<= 1) {
    s += __shfl_xor(s, msk);
    ss += __shfl_xor(ss, msk);
  }
  float mu = s * (1.0f / ND);
  float var = ss * (1.0f / ND) - mu * mu;
  float rr = rsqrtf(var + 1e-6f);
  const float4* g4 = (const float4*)g;
  const float4* b4 = (const float4*)bta;
  float4 g0 = g4[l], g1 = g4[64 + l], b0 = b4[l], b1 = b4[64 + l];
  ushort4 o0, o1;
  o0.x = f2b((a.x - mu) * rr * g0.x + b0.x);
  o0.y = f2b((a.y - mu) * rr * g0.y + b0.y);
  o0.z = f2b((a.z - mu) * rr * g0.z + b0.z);
  o0.w = f2b((a.w - mu) * rr * g0.w + b0.w);
  o1.x = f2b((bq.x - mu) * rr * g1.x + b1.x);
  o1.y = f2b((bq.y - mu) * rr * g1.y + b1.y);
  o1.z = f2b((bq.z - mu) * rr * g1.z + b1.z);
  o1.w = f2b((bq.w - mu) * rr * g1.w + b1.w);
  ushort4* orow = (ushort4*)(out + row * ND);
  orow[l] = o0;
  orow[64 + l] = o1;
}

// ---------------- MFMA GEMM: C[M][N] = A[M][K] * Bt[N][K]^T ----------------
// 128x128 tile, BK=64, 4 waves, 2-buffer dbuf. Per iter: stage next K-tile
// (8 gload_lds), wait vmcnt(8) (next stays in flight), barrier, 2 x
// {8 ds_read_b128 + 16 MFMA}, barrier. T2 XOR-swizzle (byte ^= ((row&7)<<4))
// applied source-side (linear LDS dest, inverse-swizzled global src) and on
// ds_read addresses -> 16-way bank conflict becomes 2-way (free).
// Bijective XCD swizzle; setprio around MFMA clusters.
template <int EPI>
__global__ __launch_bounds__(256) void gemm_bt(const unsigned short* __restrict__ A,
                                               const unsigned short* __restrict__ Bt,
                                               int M, int N, int K,
                                               unsigned short* __restrict__ ob,
                                               float* __restrict__ of,
                                               const float* __restrict__ addf,
                                               const float* __restrict__ bias) {
  __shared__ unsigned short lA[2][128 * 64];
  __shared__ unsigned short lB[2][128 * 64];
  const int t = threadIdx.x;
  const int l = t & 63, w = t >> 6;
  const int wr = w >> 1, wc = w & 1;
  const int gx = gridDim.x;
  const int nwg = gx * gridDim.y;
  const int fid = blockIdx.y * gx + blockIdx.x;
  const int q8 = nwg >> 3, r8 = nwg & 7, xcd = fid & 7, idx = fid >> 3;
  const int lid = (xcd < r8 ? xcd * (q8 + 1) : r8 * (q8 + 1) + (xcd - r8) * q8) + idx;
  const int bm = lid / gx, bn = lid % gx;
  const size_t rowBytes = (size_t)K * 2;
  const char* Ab = (const char*)A + (size_t)bm * 128 * rowBytes;
  const char* Bb = (const char*)Bt + (size_t)bn * 128 * rowBytes;
  // staging: thread covers rows (t>>3)+32i, swizzled byte-col within the row
  const int srow0 = t >> 3;
  const int scb = (((t & 7) ^ ((t >> 3) & 7)) << 4);
  f32x4 acc[4][4] = {};

  auto stage = [&](int buf, int k0) {
    char* dA = (char*)&lA[buf][0] + t * 16;
    char* dB = (char*)&lB[buf][0] + t * 16;
#pragma unroll
    for (int i = 0; i < 4; ++i) {
      const size_t go = (size_t)(srow0 + i * 32) * rowBytes + 2 * k0 + scb;
      gload16(Ab + go, dA + i * 4096);
      gload16(Bb + go, dB + i * 4096);
    }
  };

  const int nkt = K >> 6;
  stage(0, 0);
  int cur = 0;
  for (int kt = 0; kt < nkt; ++kt) {
    if (kt + 1 < nkt) {
      stage(cur ^ 1, (kt + 1) * 64);
      asm volatile("s_waitcnt vmcnt(8)" ::: "memory");
    } else {
      asm volatile("s_waitcnt vmcnt(0)" ::: "memory");
    }
    __builtin_amdgcn_s_barrier();
    __builtin_amdgcn_sched_barrier(0);
#pragma unroll
    for (int ks = 0; ks < 2; ++ks) {
      const int xg = ((ks * 4 + (l >> 4)) ^ (l & 7)) * 8;  // swizzled 8-elem group
      bf16x8 aF[4], bF[4];
#pragma unroll
      for (int m = 0; m < 4; ++m)
        aF[m] = *(const bf16x8*)&lA[cur][(wr * 64 + m * 16 + (l & 15)) * 64 + xg];
#pragma unroll
      for (int n = 0; n < 4; ++n)
        bF[n] = *(const bf16x8*)&lB[cur][(wc * 64 + n * 16 + (l & 15)) * 64 + xg];
      __builtin_amdgcn_s_setprio(1);
#pragma unroll
      for (int m = 0; m < 4; ++m)
#pragma unroll
        for (int n = 0; n < 4; ++n)
          acc[m][n] = __builtin_amdgcn_mfma_f32_16x16x32_bf16(aF[m], bF[n], acc[m][n], 0, 0, 0);
      __builtin_amdgcn_s_setprio(0);
    }
    asm volatile("s_waitcnt lgkmcnt(0)" ::: "memory");
    __builtin_amdgcn_s_barrier();
    cur ^= 1;
  }
#pragma unroll
  for (int m = 0; m < 4; ++m)
#pragma unroll
    for (int n = 0; n < 4; ++n) {
      int row0 = bm * 128 + wr * 64 + m * 16 + (l >> 4) * 4;
      int col = bn * 128 + wc * 64 + n * 16 + (l & 15);
      if constexpr (EPI == 0) {
        int part = col >> 9, nn = col & 511;
        int hh = nn >> 6, hd = nn & 63;
        int b = row0 >> 12, sidx0 = row0 & 4095;
        if (part < 2) {
#pragma unroll
          for (int j = 0; j < 4; ++j)
            ob[((((size_t)part * NB + b) * NH + hh) * NS + sidx0 + j) * NHD + hd] =
                f2b(acc[m][n][j]);
        } else {
          ushort4 o;
          o.x = f2b(acc[m][n][0]);
          o.y = f2b(acc[m][n][1]);
          o.z = f2b(acc[m][n][2]);
          o.w = f2b(acc[m][n][3]);
          // V^T: [B][H][HD][S], third segment of the qkv buffer
          *(ushort4*)&ob[(size_t)2 * NB * NH * NS * NHD +
                         (((size_t)b * NH + hh) * NHD + hd) * NS + sidx0] = o;
        }
      } else {
#pragma unroll
        for (int j = 0; j < 4; ++j) {
          int row = row0 + j;
          float v = acc[m][n][j];
          if constexpr (EPI == 1) {
            size_t i = (size_t)row * ND + col;
            of[i] = v + addf[i];
          } else if constexpr (EPI == 2) {
            size_t i = (size_t)row * NMLP + col;
            ob[i] = f2b(geluf(v + bias[col]));
          } else if constexpr (EPI == 3) {
            size_t i = (size_t)row * ND + col;
            of[i] = v + bias[col] + addf[i];
          }
        }
      }
    }
}

// ---------------- block-sparse flash attention ----------------
// 8 waves x 16 q-rows, 128-key chunks. K staged [128][72] from [B][H][S][HD];
// V staged [64][136] from global V^T [B][H][HD][S] (vector ops, conflict-free).
// Local block computed triangularly; reg-prefetch of next chunk under compute.
__global__ __launch_bounds__(512, 4) void attn_sparse(const unsigned short* __restrict__ qm,
                                                      const unsigned short* __restrict__ km,
                                                      const unsigned short* __restrict__ vTg,
                                                      unsigned short* __restrict__ ctx) {
  __shared__ unsigned short kl[128 * 72];
  __shared__ unsigned short vt[64 * 136];
  __shared__ unsigned short pl[8][16 * 72];
  const int t = threadIdx.x, l = t & 63, w = t >> 6;
  const int bid = blockIdx.x;
  const int qbRaw = bid & 31, hh = (bid >> 5) & 7, b = bid >> 8;
  const int qb = b ? (31 - qbRaw) : qbRaw;  // work-complement pairing across batch
  const size_t bh = ((size_t)b * NH + hh) * NS;
  const size_t bhd = ((size_t)b * NH + hh) * NHD;
  const int qrow0 = qb * 128 + w * 16;
  bf16x8 qa[2];
#pragma unroll
  for (int ks = 0; ks < 2; ++ks)
    qa[ks] = *(const bf16x8*)&qm[(bh + qrow0 + (l & 15)) * NHD + ks * 32 + (l >> 4) * 8];
  f32x4 c[4] = {};
  float mrun[4], lrun[4];
#pragma unroll
  for (int j = 0; j < 4; ++j) { mrun[j] = -1e30f; lrun[j] = 0.0f; }

  const int nsum128 = qb >> 2, rem = qb & 3;
  const int nSumCh = nsum128 + (rem ? 1 : 0);
  const int nch = nSumCh + 1;
  const int kkey = t >> 2, kd = (t & 3) * 16;
  const int vd = t >> 3, vk = (t & 7) * 16;

  s16x8 kr0, kr1, vr0, vr1;
  auto issueLoads = [&](int c2) {
    int grK, sV;
    if (c2 < nSumCh) {
      grK = ((c2 << 2) + (kkey >> 5)) * 128 + 96 + (kkey & 31);
      sV = ((c2 << 2) + (vk >> 5)) * 128 + 96 + (vk & 31);
    } else {
      grK = qb * 128 + kkey;
      sV = qb * 128 + vk;
    }
    const unsigned short* kp = &km[(bh + grK) * NHD + kd];
    kr0 = *(const s16x8*)kp;
    kr1 = *(const s16x8*)(kp + 8);
    const unsigned short* vp = &vTg[(bhd + vd) * NS + sV];
    vr0 = *(const s16x8*)vp;
    vr1 = *(const s16x8*)(vp + 8);
  };

  issueLoads(0);
  for (int ch = 0; ch < nch; ++ch) {
    if (ch) {
      asm volatile("s_waitcnt lgkmcnt(0)" ::: "memory");
      __builtin_amdgcn_s_barrier();
    }
    *(s16x8*)&kl[kkey * 72 + kd] = kr0;
    *(s16x8*)&kl[kkey * 72 + kd + 8] = kr1;
    *(s16x8*)&vt[vd * 136 + vk] = vr0;
    *(s16x8*)&vt[vd * 136 + vk + 8] = vr1;
    asm volatile("s_waitcnt lgkmcnt(0)" ::: "memory");
    __builtin_amdgcn_s_barrier();
    __builtin_amdgcn_sched_barrier(0);
    if (ch + 1 < nch) issueLoads(ch + 1);

    const bool isLocal = (ch == nch - 1);
    const bool isRem = (rem != 0) && !isLocal && (ch == nsum128);
    const int nT = isLocal ? (w + 1) : (isRem ? 2 * rem : 8);
    const int nTpl = isLocal ? ((w | 1) + 1) : nT;
    const int nKs = nTpl >> 1;

    f32x4 sf[8];
#pragma unroll
    for (int n = 0; n < 8; ++n) {
      if (n < nT) {
        const bf16x8 k0 = *(const bf16x8*)&kl[(n * 16 + (l & 15)) * 72 + (l >> 4) * 8];
        const bf16x8 k1 = *(const bf16x8*)&kl[(n * 16 + (l & 15)) * 72 + 32 + (l >> 4) * 8];
        f32x4 a = {};
        a = __builtin_amdgcn_mfma_f32_16x16x32_bf16(qa[0], k0, a, 0, 0, 0);
        a = __builtin_amdgcn_mfma_f32_16x16x32_bf16(qa[1], k1, a, 0, 0, 0);
        if (isLocal && n == w) {
#pragma unroll
          for (int j = 0; j < 4; ++j)
            if ((l & 15) > (l >> 4) * 4 + j) a[j] = -1e9f;
        }
        sf[n] = a;
      }
    }
    float cm[4], al[4];
#pragma unroll
    for (int j = 0; j < 4; ++j) cm[j] = -1e30f;
#pragma unroll
    for (int n = 0; n < 8; ++n)
      if (n < nT)
#pragma unroll
        for (int j = 0; j < 4; ++j) cm[j] = fmaxf(cm[j], sf[n][j]);
#pragma unroll
    for (int j = 0; j < 4; ++j) {
      cm[j] = fmaxf(cm[j], __shfl_xor(cm[j], 1));
      cm[j] = fmaxf(cm[j], __shfl_xor(cm[j], 2));
      cm[j] = fmaxf(cm[j], __shfl_xor(cm[j], 4));
      cm[j] = fmaxf(cm[j], __shfl_xor(cm[j], 8));
      float nm = fmaxf(mrun[j], cm[j]);
      al[j] = __expf(mrun[j] - nm);
      mrun[j] = nm;
    }
#pragma unroll
    for (int n = 0; n < 4; ++n)
#pragma unroll
      for (int j = 0; j < 4; ++j) c[n][j] *= al[j];
    float rs[4] = {0.f, 0.f, 0.f, 0.f};
#pragma unroll
    for (int n = 0; n < 8; ++n)
      if (n < nT)
#pragma unroll
        for (int j = 0; j < 4; ++j) {
          float p = __expf(sf[n][j] - mrun[j]);
          sf[n][j] = p;
          rs[j] += p;
        }
#pragma unroll
    for (int j = 0; j < 4; ++j) {
      rs[j] += __shfl_xor(rs[j], 1);
      rs[j] += __shfl_xor(rs[j], 2);
      rs[j] += __shfl_xor(rs[j], 4);
      rs[j] += __shfl_xor(rs[j], 8);
      lrun[j] = lrun[j] * al[j] + rs[j];
    }
#pragma unroll
    for (int h = 0; h < 2; ++h) {
      if (h * 4 < nTpl) {
#pragma unroll
        for (int n2 = 0; n2 < 4; ++n2) {
          const int n = h * 4 + n2;
#pragma unroll
          for (int j = 0; j < 4; ++j) {
            if (n < nTpl) {
              unsigned short pv = 0;
              if (n < nT) pv = f2b(sf[n][j]);
              pl[w][((l >> 4) * 4 + j) * 72 + n2 * 16 + (l & 15)] = pv;
            }
          }
        }
#pragma unroll
        for (int ks2 = 0; ks2 < 2; ++ks2) {
          const int ks = h * 2 + ks2;
          if (ks < nKs) {
            const bf16x8 pa = *(const bf16x8*)&pl[w][(l & 15) * 72 + ks2 * 32 + (l >> 4) * 8];
#pragma unroll
            for (int nd = 0; nd < 4; ++nd) {
              const bf16x8 vb =
                  *(const bf16x8*)&vt[(nd * 16 + (l & 15)) * 136 + ks * 32 + (l >> 4) * 8];
              c[nd] = __builtin_amdgcn_mfma_f32_16x16x32_bf16(pa, vb, c[nd], 0, 0, 0);
            }
          }
        }
      }
    }
  }
#pragma unroll
  for (int n = 0; n < 4; ++n)
#pragma unroll
    for (int j = 0; j < 4; ++j) {
      int srow = qrow0 + (l >> 4) * 4 + j;
      int col = n * 16 + (l & 15);
      ctx[((size_t)b * NS + srow) * ND + hh * NHD + col] = f2b(c[n][j] / lrun[j]);
    }
}

extern "C" void kernel_launch(void* const* d_in, const int* in_sizes, int n_in,
                              void* d_out, int out_size, void* d_ws, size_t ws_size,
                              hipStream_t stream) {
  (void)in_sizes; (void)n_in; (void)out_size; (void)ws_size;
  const float* inputs = (const float*)d_in[0];
  const float* ln1s = (const float*)d_in[1];
  const float* ln1b = (const float*)d_in[2];
  const float* wq = (const float*)d_in[3];
  const float* wk = (const float*)d_in[4];
  const float* wv = (const float*)d_in[5];
  const float* wo = (const float*)d_in[6];
  const float* ln2s = (const float*)d_in[7];
  const float* ln2b = (const float*)d_in[8];
  const float* w1 = (const float*)d_in[9];
  const float* b1 = (const float*)d_in[10];
  const float* w2 = (const float*)d_in[11];
  const float* b2 = (const float*)d_in[12];
  float* out = (float*)d_out;

  // workspace layout (~102 MB)
  unsigned short* xln = (unsigned short*)d_ws;                 // 8192*512 bf16
  unsigned short* xln2 = xln + (size_t)8192 * 512;             // 8192*512
  unsigned short* ctx = xln2 + (size_t)8192 * 512;             // 8192*512
  unsigned short* qkv = ctx + (size_t)8192 * 512;              // 3 * 8192*512 (Q, K, V^T)
  float* xres = (float*)(qkv + (size_t)3 * 8192 * 512);        // 8192*512 fp32
  unsigned short* hbuf = (unsigned short*)(xres + (size_t)8192 * 512);  // 8192*2048
  unsigned short* qkvT = hbuf + (size_t)8192 * 2048;           // 1536*512
  unsigned short* woT = qkvT + (size_t)1536 * 512;             // 512*512
  unsigned short* w1T = woT + (size_t)512 * 512;               // 2048*512
  unsigned short* w2T = w1T + (size_t)2048 * 512;              // 512*2048

  prep_weights<<<768, 256, 0, stream>>>(wq, wk, wv, wo, w1, w2, qkvT, woT, w1T, w2T);
  ln_bf16<<<2048, 256, 0, stream>>>(inputs, ln1s, ln1b, xln);
  gemm_bt<0><<<dim3(12, 64), 256, 0, stream>>>(xln, qkvT, 8192, 1536, 512,
                                               qkv, nullptr, nullptr, nullptr);
  attn_sparse<<<512, 512, 0, stream>>>(qkv, qkv + (size_t)8192 * 512,
                                       qkv + (size_t)2 * 8192 * 512, ctx);
  gemm_bt<1><<<dim3(4, 64), 256, 0, stream>>>(ctx, woT, 8192, 512, 512,
                                              nullptr, xres, inputs, nullptr);
  ln_bf16<<<2048, 256, 0, stream>>>(xres, ln2s, ln2b, xln2);
  gemm_bt<2><<<dim3(16, 64), 256, 0, stream>>>(xln2, w1T, 8192, 2048, 512,
                                               hbuf, nullptr, nullptr, b1);
  gemm_bt<3><<<dim3(4, 64), 256, 0, stream>>>(hbuf, w2T, 8192, 512, 2048,
                                              nullptr, out, xres, b2);
}

// Round 7
// 164.375 us; speedup vs baseline: 1.6979x; 1.0481x over previous
//
#include <hip/hip_runtime.h>
#include <hip/hip_bf16.h>

typedef __attribute__((ext_vector_type(8))) __bf16 bf16x8;
typedef __attribute__((ext_vector_type(8))) short s16x8;
typedef __attribute__((ext_vector_type(4))) float f32x4;

#define NB 2
#define NS 4096
#define ND 512
#define NH 8
#define NHD 64
#define NMLP 2048

__device__ __forceinline__ unsigned short f2b(float f) {
  __hip_bfloat16 h = __float2bfloat16(f);
  return __builtin_bit_cast(unsigned short, h);
}

// gelu(x) = 0.5x(1+tanh(u)) = x * sigmoid(2u), u = 0.79788456(x + 0.044715 x^3)
// branch-free fast form: exp overflow/underflow saturates correctly.
__device__ __forceinline__ float geluf(float x) {
  float u = 0.7978845608028654f * (x + 0.044715f * x * x * x);
  return x / (1.0f + __expf(-2.0f * u));
}

__device__ __forceinline__ void gload16(const void* g, void* l) {
  __builtin_amdgcn_global_load_lds((const __attribute__((address_space(1))) void*)g,
                                   (__attribute__((address_space(3))) void*)l, 16, 0, 0);
}

// ---------------- weight transposes: 64x64 LDS-tiled, one launch ----------------
__global__ __launch_bounds__(256) void prep_weights(const float* __restrict__ wq,
                                                    const float* __restrict__ wk,
                                                    const float* __restrict__ wv,
                                                    const float* __restrict__ wo,
                                                    const float* __restrict__ w1,
                                                    const float* __restrict__ w2,
                                                    unsigned short* __restrict__ qkvT,
                                                    unsigned short* __restrict__ woT,
                                                    unsigned short* __restrict__ w1T,
                                                    unsigned short* __restrict__ w2T) {
  __shared__ unsigned short lt[64][66];
  const int tile = blockIdx.x, t = threadIdx.x;
  const float* src;
  unsigned short* dst;
  int R, C, tr, tc;
  float sc = 1.0f;
  if (tile < 256) {
    int seg = tile >> 6, tt = tile & 63;
    R = 512; C = 512;
    src = seg == 0 ? wq : seg == 1 ? wk : seg == 2 ? wv : wo;
    dst = (seg < 3) ? (qkvT + ((size_t)seg << 18)) : woT;
    if (seg == 0) sc = 0.125f;
    tr = tt >> 3; tc = tt & 7;
  } else if (tile < 512) {
    int tt = tile - 256;
    R = 512; C = 2048; src = w1; dst = w1T;
    tr = tt >> 5; tc = tt & 31;
  } else {
    int tt = tile - 512;
    R = 2048; C = 512; src = w2; dst = w2T;
    tr = tt >> 3; tc = tt & 7;
  }
  const int r0 = tr * 64, c0 = tc * 64;
  const int fx = t & 15, fy = t >> 4;
#pragma unroll
  for (int p = 0; p < 4; ++p) {
    int rr = p * 16 + fy;
    float4 v = *(const float4*)&src[(size_t)(r0 + rr) * C + c0 + fx * 4];
    lt[rr][fx * 4 + 0] = f2b(v.x * sc);
    lt[rr][fx * 4 + 1] = f2b(v.y * sc);
    lt[rr][fx * 4 + 2] = f2b(v.z * sc);
    lt[rr][fx * 4 + 3] = f2b(v.w * sc);
  }
  __syncthreads();
#pragma unroll
  for (int p = 0; p < 4; ++p) {
    int cc = p * 16 + fy;
    ushort4 o;
    o.x = lt[fx * 4 + 0][cc];
    o.y = lt[fx * 4 + 1][cc];
    o.z = lt[fx * 4 + 2][cc];
    o.w = lt[fx * 4 + 3][cc];
    *(ushort4*)&dst[(size_t)(c0 + cc) * R + r0 + fx * 4] = o;
  }
}

// ---------------- LayerNorm fp32 -> bf16, one wave per row (D=512) ----------------
__global__ __launch_bounds__(256) void ln_bf16(const float* __restrict__ x,
                                               const float* __restrict__ g,
                                               const float* __restrict__ bta,
                                               unsigned short* __restrict__ out) {
  const int t = threadIdx.x, l = t & 63, w = t >> 6;
  const size_t row = (size_t)blockIdx.x * 4 + w;
  const float4* xr = (const float4*)(x + row * ND);
  float4 a = xr[l];
  float4 bq = xr[64 + l];
  float s = a.x + a.y + a.z + a.w + bq.x + bq.y + bq.z + bq.w;
  float ss = a.x * a.x + a.y * a.y + a.z * a.z + a.w * a.w +
             bq.x * bq.x + bq.y * bq.y + bq.z * bq.z + bq.w * bq.w;
#pragma unroll
  for (int msk = 1; msk <= 32; msk <<= 1) {
    s += __shfl_xor(s, msk);
    ss += __shfl_xor(ss, msk);
  }
  float mu = s * (1.0f / ND);
  float var = ss * (1.0f / ND) - mu * mu;
  float rr = rsqrtf(var + 1e-6f);
  const float4* g4 = (const float4*)g;
  const float4* b4 = (const float4*)bta;
  float4 g0 = g4[l], g1 = g4[64 + l], b0 = b4[l], b1 = b4[64 + l];
  ushort4 o0, o1;
  o0.x = f2b((a.x - mu) * rr * g0.x + b0.x);
  o0.y = f2b((a.y - mu) * rr * g0.y + b0.y);
  o0.z = f2b((a.z - mu) * rr * g0.z + b0.z);
  o0.w = f2b((a.w - mu) * rr * g0.w + b0.w);
  o1.x = f2b((bq.x - mu) * rr * g1.x + b1.x);
  o1.y = f2b((bq.y - mu) * rr * g1.y + b1.y);
  o1.z = f2b((bq.z - mu) * rr * g1.z + b1.z);
  o1.w = f2b((bq.w - mu) * rr * g1.w + b1.w);
  ushort4* orow = (ushort4*)(out + row * ND);
  orow[l] = o0;
  orow[64 + l] = o1;
}

// ---------------- 256x256 MFMA GEMM (8 waves, BK=64, dbuf, swizzled LDS) ----------
// Wave grid 2x4, per-wave tile 128x64 (acc 8x4) -> 43.7 FLOP per LDS byte vs 32
// for the 128^2 kernel. Same counted-vmcnt discipline and same XOR swizzle
// (LDS[row][slot] holds global slot^(row&7); read slot s^(l&7)).
// EPI: 0 = QKV scatter (Q,K -> [B][H][S][HD]; V -> transposed [B][H][HD][S]);
//      2 = gelu(+b1) -> bf16.
template <int EPI>
__global__ __launch_bounds__(512, 2) void gemm256(const unsigned short* __restrict__ A,
                                                  const unsigned short* __restrict__ Bt,
                                                  int M, int N, int K,
                                                  unsigned short* __restrict__ ob,
                                                  const float* __restrict__ bias) {
  __shared__ unsigned short lA[2][256 * 64];
  __shared__ unsigned short lB[2][256 * 64];
  const int t = threadIdx.x, l = t & 63, w = t >> 6;
  const int wr = w >> 2, wc = w & 3;
  const int gx = gridDim.x;
  const int nwg = gx * gridDim.y;
  const int fid = blockIdx.y * gx + blockIdx.x;
  const int q8 = nwg >> 3, r8 = nwg & 7, xcd = fid & 7, idx = fid >> 3;
  const int lid = (xcd < r8 ? xcd * (q8 + 1) : r8 * (q8 + 1) + (xcd - r8) * q8) + idx;
  const int bm = lid / gx, bn = lid % gx;
  const size_t rowBytes = (size_t)K * 2;
  const char* Ab = (const char*)A + (size_t)bm * 256 * rowBytes;
  const char* Bb = (const char*)Bt + (size_t)bn * 256 * rowBytes;
  const int srow0 = t >> 3;
  const int scb = (((t & 7) ^ ((t >> 3) & 7)) << 4);
  f32x4 acc[8][4] = {};

  auto stage = [&](int buf, int k0) {
    char* dA = (char*)&lA[buf][0] + t * 16;
    char* dB = (char*)&lB[buf][0] + t * 16;
#pragma unroll
    for (int i = 0; i < 4; ++i) {
      const size_t go = (size_t)(srow0 + i * 64) * rowBytes + 2 * k0 + scb;
      gload16(Ab + go, dA + i * 8192);
      gload16(Bb + go, dB + i * 8192);
    }
  };

  const int nkt = K >> 6;
  stage(0, 0);
  int cur = 0;
  for (int kt = 0; kt < nkt; ++kt) {
    if (kt + 1 < nkt) {
      stage(cur ^ 1, (kt + 1) * 64);
      asm volatile("s_waitcnt vmcnt(8)" ::: "memory");
    } else {
      asm volatile("s_waitcnt vmcnt(0)" ::: "memory");
    }
    __builtin_amdgcn_s_barrier();
    __builtin_amdgcn_sched_barrier(0);
#pragma unroll
    for (int ks = 0; ks < 2; ++ks) {
      const int xg = ((ks * 4 + (l >> 4)) ^ (l & 7)) * 8;
      bf16x8 aF[8], bF[4];
#pragma unroll
      for (int m = 0; m < 8; ++m)
        aF[m] = *(const bf16x8*)&lA[cur][(wr * 128 + m * 16 + (l & 15)) * 64 + xg];
#pragma unroll
      for (int n = 0; n < 4; ++n)
        bF[n] = *(const bf16x8*)&lB[cur][(wc * 64 + n * 16 + (l & 15)) * 64 + xg];
      asm volatile("s_waitcnt lgkmcnt(0)" ::: "memory");
      __builtin_amdgcn_sched_barrier(0);
      __builtin_amdgcn_s_setprio(1);
#pragma unroll
      for (int m = 0; m < 8; ++m)
#pragma unroll
        for (int n = 0; n < 4; ++n)
          acc[m][n] = __builtin_amdgcn_mfma_f32_16x16x32_bf16(aF[m], bF[n], acc[m][n], 0, 0, 0);
      __builtin_amdgcn_s_setprio(0);
    }
    asm volatile("s_waitcnt lgkmcnt(0)" ::: "memory");
    __builtin_amdgcn_s_barrier();
    cur ^= 1;
  }
#pragma unroll
  for (int m = 0; m < 8; ++m)
#pragma unroll
    for (int n = 0; n < 4; ++n) {
      int row0 = bm * 256 + wr * 128 + m * 16 + (l >> 4) * 4;
      int col = bn * 256 + wc * 64 + n * 16 + (l & 15);
      if constexpr (EPI == 0) {
        int part = col >> 9, nn = col & 511;
        int hh = nn >> 6, hd = nn & 63;
        int b = row0 >> 12, sidx0 = row0 & 4095;
        if (part < 2) {
#pragma unroll
          for (int j = 0; j < 4; ++j)
            ob[((((size_t)part * NB + b) * NH + hh) * NS + sidx0 + j) * NHD + hd] =
                f2b(acc[m][n][j]);
        } else {
          ushort4 o;
          o.x = f2b(acc[m][n][0]);
          o.y = f2b(acc[m][n][1]);
          o.z = f2b(acc[m][n][2]);
          o.w = f2b(acc[m][n][3]);
          *(ushort4*)&ob[(size_t)2 * NB * NH * NS * NHD +
                         (((size_t)b * NH + hh) * NHD + hd) * NS + sidx0] = o;
        }
      } else {
#pragma unroll
        for (int j = 0; j < 4; ++j) {
          size_t i = (size_t)(row0 + j) * NMLP + col;
          ob[i] = f2b(geluf(acc[m][n][j] + bias[col]));
        }
      }
    }
}

// ---------------- 128x128 MFMA GEMM (4 waves, BK=64, dbuf, swizzled) ----------------
// Used for the N=512 GEMMs (AO, MLP2) where 256-wide tiles would idle 75% of CUs.
// EPI: 1 = +inputs -> fp32 xres; 3 = +b2 +xres -> fp32 out.
template <int EPI>
__global__ __launch_bounds__(256) void gemm_bt(const unsigned short* __restrict__ A,
                                               const unsigned short* __restrict__ Bt,
                                               int M, int N, int K,
                                               float* __restrict__ of,
                                               const float* __restrict__ addf,
                                               const float* __restrict__ bias) {
  __shared__ unsigned short lA[2][128 * 64];
  __shared__ unsigned short lB[2][128 * 64];
  const int t = threadIdx.x;
  const int l = t & 63, w = t >> 6;
  const int wr = w >> 1, wc = w & 1;
  const int gx = gridDim.x;
  const int nwg = gx * gridDim.y;
  const int fid = blockIdx.y * gx + blockIdx.x;
  const int q8 = nwg >> 3, r8 = nwg & 7, xcd = fid & 7, idx = fid >> 3;
  const int lid = (xcd < r8 ? xcd * (q8 + 1) : r8 * (q8 + 1) + (xcd - r8) * q8) + idx;
  const int bm = lid / gx, bn = lid % gx;
  const size_t rowBytes = (size_t)K * 2;
  const char* Ab = (const char*)A + (size_t)bm * 128 * rowBytes;
  const char* Bb = (const char*)Bt + (size_t)bn * 128 * rowBytes;
  const int srow0 = t >> 3;
  const int scb = (((t & 7) ^ ((t >> 3) & 7)) << 4);
  f32x4 acc[4][4] = {};

  auto stage = [&](int buf, int k0) {
    char* dA = (char*)&lA[buf][0] + t * 16;
    char* dB = (char*)&lB[buf][0] + t * 16;
#pragma unroll
    for (int i = 0; i < 4; ++i) {
      const size_t go = (size_t)(srow0 + i * 32) * rowBytes + 2 * k0 + scb;
      gload16(Ab + go, dA + i * 4096);
      gload16(Bb + go, dB + i * 4096);
    }
  };

  const int nkt = K >> 6;
  stage(0, 0);
  int cur = 0;
  for (int kt = 0; kt < nkt; ++kt) {
    if (kt + 1 < nkt) {
      stage(cur ^ 1, (kt + 1) * 64);
      asm volatile("s_waitcnt vmcnt(8)" ::: "memory");
    } else {
      asm volatile("s_waitcnt vmcnt(0)" ::: "memory");
    }
    __builtin_amdgcn_s_barrier();
    __builtin_amdgcn_sched_barrier(0);
#pragma unroll
    for (int ks = 0; ks < 2; ++ks) {
      const int xg = ((ks * 4 + (l >> 4)) ^ (l & 7)) * 8;
      bf16x8 aF[4], bF[4];
#pragma unroll
      for (int m = 0; m < 4; ++m)
        aF[m] = *(const bf16x8*)&lA[cur][(wr * 64 + m * 16 + (l & 15)) * 64 + xg];
#pragma unroll
      for (int n = 0; n < 4; ++n)
        bF[n] = *(const bf16x8*)&lB[cur][(wc * 64 + n * 16 + (l & 15)) * 64 + xg];
      __builtin_amdgcn_s_setprio(1);
#pragma unroll
      for (int m = 0; m < 4; ++m)
#pragma unroll
        for (int n = 0; n < 4; ++n)
          acc[m][n] = __builtin_amdgcn_mfma_f32_16x16x32_bf16(aF[m], bF[n], acc[m][n], 0, 0, 0);
      __builtin_amdgcn_s_setprio(0);
    }
    asm volatile("s_waitcnt lgkmcnt(0)" ::: "memory");
    __builtin_amdgcn_s_barrier();
    cur ^= 1;
  }
#pragma unroll
  for (int m = 0; m < 4; ++m)
#pragma unroll
    for (int n = 0; n < 4; ++n) {
      int row0 = bm * 128 + wr * 64 + m * 16 + (l >> 4) * 4;
      int col = bn * 128 + wc * 64 + n * 16 + (l & 15);
#pragma unroll
      for (int j = 0; j < 4; ++j) {
        int row = row0 + j;
        float v = acc[m][n][j];
        if constexpr (EPI == 1) {
          size_t i = (size_t)row * ND + col;
          of[i] = v + addf[i];
        } else {
          size_t i = (size_t)row * ND + col;
          of[i] = v + bias[col] + addf[i];
        }
      }
    }
}

// ---------------- block-sparse flash attention ----------------
// 8 waves x 16 q-rows, 128-key chunks. K staged [128][72] from [B][H][S][HD];
// V staged [64][136] from global V^T [B][H][HD][S] (vector ops, conflict-free).
// Local block computed triangularly; reg-prefetch of next chunk under compute.
__global__ __launch_bounds__(512, 4) void attn_sparse(const unsigned short* __restrict__ qm,
                                                      const unsigned short* __restrict__ km,
                                                      const unsigned short* __restrict__ vTg,
                                                      unsigned short* __restrict__ ctx) {
  __shared__ unsigned short kl[128 * 72];
  __shared__ unsigned short vt[64 * 136];
  __shared__ unsigned short pl[8][16 * 72];
  const int t = threadIdx.x, l = t & 63, w = t >> 6;
  const int bid = blockIdx.x;
  const int qbRaw = bid & 31, hh = (bid >> 5) & 7, b = bid >> 8;
  const int qb = b ? (31 - qbRaw) : qbRaw;  // work-complement pairing across batch
  const size_t bh = ((size_t)b * NH + hh) * NS;
  const size_t bhd = ((size_t)b * NH + hh) * NHD;
  const int qrow0 = qb * 128 + w * 16;
  bf16x8 qa[2];
#pragma unroll
  for (int ks = 0; ks < 2; ++ks)
    qa[ks] = *(const bf16x8*)&qm[(bh + qrow0 + (l & 15)) * NHD + ks * 32 + (l >> 4) * 8];
  f32x4 c[4] = {};
  float mrun[4], lrun[4];
#pragma unroll
  for (int j = 0; j < 4; ++j) { mrun[j] = -1e30f; lrun[j] = 0.0f; }

  const int nsum128 = qb >> 2, rem = qb & 3;
  const int nSumCh = nsum128 + (rem ? 1 : 0);
  const int nch = nSumCh + 1;
  const int kkey = t >> 2, kd = (t & 3) * 16;
  const int vd = t >> 3, vk = (t & 7) * 16;

  s16x8 kr0, kr1, vr0, vr1;
  auto issueLoads = [&](int c2) {
    int grK, sV;
    if (c2 < nSumCh) {
      grK = ((c2 << 2) + (kkey >> 5)) * 128 + 96 + (kkey & 31);
      sV = ((c2 << 2) + (vk >> 5)) * 128 + 96 + (vk & 31);
    } else {
      grK = qb * 128 + kkey;
      sV = qb * 128 + vk;
    }
    const unsigned short* kp = &km[(bh + grK) * NHD + kd];
    kr0 = *(const s16x8*)kp;
    kr1 = *(const s16x8*)(kp + 8);
    const unsigned short* vp = &vTg[(bhd + vd) * NS + sV];
    vr0 = *(const s16x8*)vp;
    vr1 = *(const s16x8*)(vp + 8);
  };

  issueLoads(0);
  for (int ch = 0; ch < nch; ++ch) {
    if (ch) {
      asm volatile("s_waitcnt lgkmcnt(0)" ::: "memory");
      __builtin_amdgcn_s_barrier();
    }
    *(s16x8*)&kl[kkey * 72 + kd] = kr0;
    *(s16x8*)&kl[kkey * 72 + kd + 8] = kr1;
    *(s16x8*)&vt[vd * 136 + vk] = vr0;
    *(s16x8*)&vt[vd * 136 + vk + 8] = vr1;
    asm volatile("s_waitcnt lgkmcnt(0)" ::: "memory");
    __builtin_amdgcn_s_barrier();
    __builtin_amdgcn_sched_barrier(0);
    if (ch + 1 < nch) issueLoads(ch + 1);

    const bool isLocal = (ch == nch - 1);
    const bool isRem = (rem != 0) && !isLocal && (ch == nsum128);
    const int nT = isLocal ? (w + 1) : (isRem ? 2 * rem : 8);
    const int nTpl = isLocal ? ((w | 1) + 1) : nT;
    const int nKs = nTpl >> 1;

    f32x4 sf[8];
#pragma unroll
    for (int n = 0; n < 8; ++n) {
      if (n < nT) {
        const bf16x8 k0 = *(const bf16x8*)&kl[(n * 16 + (l & 15)) * 72 + (l >> 4) * 8];
        const bf16x8 k1 = *(const bf16x8*)&kl[(n * 16 + (l & 15)) * 72 + 32 + (l >> 4) * 8];
        f32x4 a = {};
        a = __builtin_amdgcn_mfma_f32_16x16x32_bf16(qa[0], k0, a, 0, 0, 0);
        a = __builtin_amdgcn_mfma_f32_16x16x32_bf16(qa[1], k1, a, 0, 0, 0);
        if (isLocal && n == w) {
#pragma unroll
          for (int j = 0; j < 4; ++j)
            if ((l & 15) > (l >> 4) * 4 + j) a[j] = -1e9f;
        }
        sf[n] = a;
      }
    }
    float cm[4], al[4];
#pragma unroll
    for (int j = 0; j < 4; ++j) cm[j] = -1e30f;
#pragma unroll
    for (int n = 0; n < 8; ++n)
      if (n < nT)
#pragma unroll
        for (int j = 0; j < 4; ++j) cm[j] = fmaxf(cm[j], sf[n][j]);
#pragma unroll
    for (int j = 0; j < 4; ++j) {
      cm[j] = fmaxf(cm[j], __shfl_xor(cm[j], 1));
      cm[j] = fmaxf(cm[j], __shfl_xor(cm[j], 2));
      cm[j] = fmaxf(cm[j], __shfl_xor(cm[j], 4));
      cm[j] = fmaxf(cm[j], __shfl_xor(cm[j], 8));
      float nm = fmaxf(mrun[j], cm[j]);
      al[j] = __expf(mrun[j] - nm);
      mrun[j] = nm;
    }
#pragma unroll
    for (int n = 0; n < 4; ++n)
#pragma unroll
      for (int j = 0; j < 4; ++j) c[n][j] *= al[j];
    float rs[4] = {0.f, 0.f, 0.f, 0.f};
#pragma unroll
    for (int n = 0; n < 8; ++n)
      if (n < nT)
#pragma unroll
        for (int j = 0; j < 4; ++j) {
          float p = __expf(sf[n][j] - mrun[j]);
          sf[n][j] = p;
          rs[j] += p;
        }
#pragma unroll
    for (int j = 0; j < 4; ++j) {
      rs[j] += __shfl_xor(rs[j], 1);
      rs[j] += __shfl_xor(rs[j], 2);
      rs[j] += __shfl_xor(rs[j], 4);
      rs[j] += __shfl_xor(rs[j], 8);
      lrun[j] = lrun[j] * al[j] + rs[j];
    }
#pragma unroll
    for (int h = 0; h < 2; ++h) {
      if (h * 4 < nTpl) {
#pragma unroll
        for (int n2 = 0; n2 < 4; ++n2) {
          const int n = h * 4 + n2;
#pragma unroll
          for (int j = 0; j < 4; ++j) {
            if (n < nTpl) {
              unsigned short pv = 0;
              if (n < nT) pv = f2b(sf[n][j]);
              pl[w][((l >> 4) * 4 + j) * 72 + n2 * 16 + (l & 15)] = pv;
            }
          }
        }
#pragma unroll
        for (int ks2 = 0; ks2 < 2; ++ks2) {
          const int ks = h * 2 + ks2;
          if (ks < nKs) {
            const bf16x8 pa = *(const bf16x8*)&pl[w][(l & 15) * 72 + ks2 * 32 + (l >> 4) * 8];
#pragma unroll
            for (int nd = 0; nd < 4; ++nd) {
              const bf16x8 vb =
                  *(const bf16x8*)&vt[(nd * 16 + (l & 15)) * 136 + ks * 32 + (l >> 4) * 8];
              c[nd] = __builtin_amdgcn_mfma_f32_16x16x32_bf16(pa, vb, c[nd], 0, 0, 0);
            }
          }
        }
      }
    }
  }
#pragma unroll
  for (int n = 0; n < 4; ++n)
#pragma unroll
    for (int j = 0; j < 4; ++j) {
      int srow = qrow0 + (l >> 4) * 4 + j;
      int col = n * 16 + (l & 15);
      ctx[((size_t)b * NS + srow) * ND + hh * NHD + col] = f2b(c[n][j] / lrun[j]);
    }
}

extern "C" void kernel_launch(void* const* d_in, const int* in_sizes, int n_in,
                              void* d_out, int out_size, void* d_ws, size_t ws_size,
                              hipStream_t stream) {
  (void)in_sizes; (void)n_in; (void)out_size; (void)ws_size;
  const float* inputs = (const float*)d_in[0];
  const float* ln1s = (const float*)d_in[1];
  const float* ln1b = (const float*)d_in[2];
  const float* wq = (const float*)d_in[3];
  const float* wk = (const float*)d_in[4];
  const float* wv = (const float*)d_in[5];
  const float* wo = (const float*)d_in[6];
  const float* ln2s = (const float*)d_in[7];
  const float* ln2b = (const float*)d_in[8];
  const float* w1 = (const float*)d_in[9];
  const float* b1 = (const float*)d_in[10];
  const float* w2 = (const float*)d_in[11];
  const float* b2 = (const float*)d_in[12];
  float* out = (float*)d_out;

  // workspace layout (~102 MB)
  unsigned short* xln = (unsigned short*)d_ws;                 // 8192*512 bf16
  unsigned short* xln2 = xln + (size_t)8192 * 512;             // 8192*512
  unsigned short* ctx = xln2 + (size_t)8192 * 512;             // 8192*512
  unsigned short* qkv = ctx + (size_t)8192 * 512;              // 3 * 8192*512 (Q, K, V^T)
  float* xres = (float*)(qkv + (size_t)3 * 8192 * 512);        // 8192*512 fp32
  unsigned short* hbuf = (unsigned short*)(xres + (size_t)8192 * 512);  // 8192*2048
  unsigned short* qkvT = hbuf + (size_t)8192 * 2048;           // 1536*512
  unsigned short* woT = qkvT + (size_t)1536 * 512;             // 512*512
  unsigned short* w1T = woT + (size_t)512 * 512;               // 2048*512
  unsigned short* w2T = w1T + (size_t)2048 * 512;              // 512*2048

  prep_weights<<<768, 256, 0, stream>>>(wq, wk, wv, wo, w1, w2, qkvT, woT, w1T, w2T);
  ln_bf16<<<2048, 256, 0, stream>>>(inputs, ln1s, ln1b, xln);
  gemm256<0><<<dim3(6, 32), 512, 0, stream>>>(xln, qkvT, 8192, 1536, 512, qkv, nullptr);
  attn_sparse<<<512, 512, 0, stream>>>(qkv, qkv + (size_t)8192 * 512,
                                       qkv + (size_t)2 * 8192 * 512, ctx);
  gemm_bt<1><<<dim3(4, 64), 256, 0, stream>>>(ctx, woT, 8192, 512, 512,
                                              xres, inputs, nullptr);
  ln_bf16<<<2048, 256, 0, stream>>>(xres, ln2s, ln2b, xln2);
  gemm256<2><<<dim3(8, 32), 512, 0, stream>>>(xln2, w1T, 8192, 2048, 512, hbuf, b1);
  gemm_bt<3><<<dim3(4, 64), 256, 0, stream>>>(hbuf, w2T, 8192, 512, 2048,
                                              out, xres, b2);
}

// Round 8
// 163.038 us; speedup vs baseline: 1.7118x; 1.0082x over previous
//
#include <hip/hip_runtime.h>
#include <hip/hip_bf16.h>

typedef __attribute__((ext_vector_type(8))) __bf16 bf16x8;
typedef __attribute__((ext_vector_type(8))) short s16x8;
typedef __attribute__((ext_vector_type(4))) float f32x4;

#define NB 2
#define NS 4096
#define ND 512
#define NH 8
#define NHD 64
#define NMLP 2048

__device__ __forceinline__ unsigned short f2b(float f) {
  __hip_bfloat16 h = __float2bfloat16(f);
  return __builtin_bit_cast(unsigned short, h);
}

// gelu(x) = 0.5x(1+tanh(u)) = x * sigmoid(2u), u = 0.79788456(x + 0.044715 x^3)
__device__ __forceinline__ float geluf(float x) {
  float u = 0.7978845608028654f * (x + 0.044715f * x * x * x);
  return x / (1.0f + __expf(-2.0f * u));
}

__device__ __forceinline__ void gload16(const void* g, void* l) {
  __builtin_amdgcn_global_load_lds((const __attribute__((address_space(1))) void*)g,
                                   (__attribute__((address_space(3))) void*)l, 16, 0, 0);
}

// ---------------- weight transposes: 64x64 LDS-tiled, one launch ----------------
__global__ __launch_bounds__(256) void prep_weights(const float* __restrict__ wq,
                                                    const float* __restrict__ wk,
                                                    const float* __restrict__ wv,
                                                    const float* __restrict__ wo,
                                                    const float* __restrict__ w1,
                                                    const float* __restrict__ w2,
                                                    unsigned short* __restrict__ qkvT,
                                                    unsigned short* __restrict__ woT,
                                                    unsigned short* __restrict__ w1T,
                                                    unsigned short* __restrict__ w2T) {
  __shared__ unsigned short lt[64][66];
  const int tile = blockIdx.x, t = threadIdx.x;
  const float* src;
  unsigned short* dst;
  int R, C, tr, tc;
  float sc = 1.0f;
  if (tile < 256) {
    int seg = tile >> 6, tt = tile & 63;
    R = 512; C = 512;
    src = seg == 0 ? wq : seg == 1 ? wk : seg == 2 ? wv : wo;
    dst = (seg < 3) ? (qkvT + ((size_t)seg << 18)) : woT;
    if (seg == 0) sc = 0.125f;
    tr = tt >> 3; tc = tt & 7;
  } else if (tile < 512) {
    int tt = tile - 256;
    R = 512; C = 2048; src = w1; dst = w1T;
    tr = tt >> 5; tc = tt & 31;
  } else {
    int tt = tile - 512;
    R = 2048; C = 512; src = w2; dst = w2T;
    tr = tt >> 3; tc = tt & 7;
  }
  const int r0 = tr * 64, c0 = tc * 64;
  const int fx = t & 15, fy = t >> 4;
#pragma unroll
  for (int p = 0; p < 4; ++p) {
    int rr = p * 16 + fy;
    float4 v = *(const float4*)&src[(size_t)(r0 + rr) * C + c0 + fx * 4];
    lt[rr][fx * 4 + 0] = f2b(v.x * sc);
    lt[rr][fx * 4 + 1] = f2b(v.y * sc);
    lt[rr][fx * 4 + 2] = f2b(v.z * sc);
    lt[rr][fx * 4 + 3] = f2b(v.w * sc);
  }
  __syncthreads();
#pragma unroll
  for (int p = 0; p < 4; ++p) {
    int cc = p * 16 + fy;
    ushort4 o;
    o.x = lt[fx * 4 + 0][cc];
    o.y = lt[fx * 4 + 1][cc];
    o.z = lt[fx * 4 + 2][cc];
    o.w = lt[fx * 4 + 3][cc];
    *(ushort4*)&dst[(size_t)(c0 + cc) * R + r0 + fx * 4] = o;
  }
}

// ---------------- LayerNorm fp32 -> bf16, one wave per row (D=512) ----------------
__global__ __launch_bounds__(256) void ln_bf16(const float* __restrict__ x,
                                               const float* __restrict__ g,
                                               const float* __restrict__ bta,
                                               unsigned short* __restrict__ out) {
  const int t = threadIdx.x, l = t & 63, w = t >> 6;
  const size_t row = (size_t)blockIdx.x * 4 + w;
  const float4* xr = (const float4*)(x + row * ND);
  float4 a = xr[l];
  float4 bq = xr[64 + l];
  float s = a.x + a.y + a.z + a.w + bq.x + bq.y + bq.z + bq.w;
  float ss = a.x * a.x + a.y * a.y + a.z * a.z + a.w * a.w +
             bq.x * bq.x + bq.y * bq.y + bq.z * bq.z + bq.w * bq.w;
#pragma unroll
  for (int msk = 1; msk <= 32; msk <<= 1) {
    s += __shfl_xor(s, msk);
    ss += __shfl_xor(ss, msk);
  }
  float mu = s * (1.0f / ND);
  float var = ss * (1.0f / ND) - mu * mu;
  float rr = rsqrtf(var + 1e-6f);
  const float4* g4 = (const float4*)g;
  const float4* b4 = (const float4*)bta;
  float4 g0 = g4[l], g1 = g4[64 + l], b0 = b4[l], b1 = b4[64 + l];
  ushort4 o0, o1;
  o0.x = f2b((a.x - mu) * rr * g0.x + b0.x);
  o0.y = f2b((a.y - mu) * rr * g0.y + b0.y);
  o0.z = f2b((a.z - mu) * rr * g0.z + b0.z);
  o0.w = f2b((a.w - mu) * rr * g0.w + b0.w);
  o1.x = f2b((bq.x - mu) * rr * g1.x + b1.x);
  o1.y = f2b((bq.y - mu) * rr * g1.y + b1.y);
  o1.z = f2b((bq.z - mu) * rr * g1.z + b1.z);
  o1.w = f2b((bq.w - mu) * rr * g1.w + b1.w);
  ushort4* orow = (ushort4*)(out + row * ND);
  orow[l] = o0;
  orow[64 + l] = o1;
}

// ---------------- 256x256 MFMA GEMM (8 waves, BK=64, dbuf, swizzled LDS) ----------
template <int EPI>
__global__ __launch_bounds__(512, 2) void gemm256(const unsigned short* __restrict__ A,
                                                  const unsigned short* __restrict__ Bt,
                                                  int M, int N, int K,
                                                  unsigned short* __restrict__ ob,
                                                  const float* __restrict__ bias) {
  __shared__ unsigned short lA[2][256 * 64];
  __shared__ unsigned short lB[2][256 * 64];
  const int t = threadIdx.x, l = t & 63, w = t >> 6;
  const int wr = w >> 2, wc = w & 3;
  const int gx = gridDim.x;
  const int nwg = gx * gridDim.y;
  const int fid = blockIdx.y * gx + blockIdx.x;
  const int q8 = nwg >> 3, r8 = nwg & 7, xcd = fid & 7, idx = fid >> 3;
  const int lid = (xcd < r8 ? xcd * (q8 + 1) : r8 * (q8 + 1) + (xcd - r8) * q8) + idx;
  const int bm = lid / gx, bn = lid % gx;
  const size_t rowBytes = (size_t)K * 2;
  const char* Ab = (const char*)A + (size_t)bm * 256 * rowBytes;
  const char* Bb = (const char*)Bt + (size_t)bn * 256 * rowBytes;
  const int srow0 = t >> 3;
  const int scb = (((t & 7) ^ ((t >> 3) & 7)) << 4);
  f32x4 acc[8][4] = {};

  auto stage = [&](int buf, int k0) {
    char* dA = (char*)&lA[buf][0] + t * 16;
    char* dB = (char*)&lB[buf][0] + t * 16;
#pragma unroll
    for (int i = 0; i < 4; ++i) {
      const size_t go = (size_t)(srow0 + i * 64) * rowBytes + 2 * k0 + scb;
      gload16(Ab + go, dA + i * 8192);
      gload16(Bb + go, dB + i * 8192);
    }
  };

  const int nkt = K >> 6;
  stage(0, 0);
  int cur = 0;
  for (int kt = 0; kt < nkt; ++kt) {
    if (kt + 1 < nkt) {
      stage(cur ^ 1, (kt + 1) * 64);
      asm volatile("s_waitcnt vmcnt(8)" ::: "memory");
    } else {
      asm volatile("s_waitcnt vmcnt(0)" ::: "memory");
    }
    __builtin_amdgcn_s_barrier();
    __builtin_amdgcn_sched_barrier(0);
#pragma unroll
    for (int ks = 0; ks < 2; ++ks) {
      const int xg = ((ks * 4 + (l >> 4)) ^ (l & 7)) * 8;
      bf16x8 aF[8], bF[4];
#pragma unroll
      for (int m = 0; m < 8; ++m)
        aF[m] = *(const bf16x8*)&lA[cur][(wr * 128 + m * 16 + (l & 15)) * 64 + xg];
#pragma unroll
      for (int n = 0; n < 4; ++n)
        bF[n] = *(const bf16x8*)&lB[cur][(wc * 64 + n * 16 + (l & 15)) * 64 + xg];
      __builtin_amdgcn_s_setprio(1);
#pragma unroll
      for (int m = 0; m < 8; ++m)
#pragma unroll
        for (int n = 0; n < 4; ++n)
          acc[m][n] = __builtin_amdgcn_mfma_f32_16x16x32_bf16(aF[m], bF[n], acc[m][n], 0, 0, 0);
      __builtin_amdgcn_s_setprio(0);
    }
    asm volatile("s_waitcnt lgkmcnt(0)" ::: "memory");
    __builtin_amdgcn_s_barrier();
    cur ^= 1;
  }
#pragma unroll
  for (int m = 0; m < 8; ++m)
#pragma unroll
    for (int n = 0; n < 4; ++n) {
      int row0 = bm * 256 + wr * 128 + m * 16 + (l >> 4) * 4;
      int col = bn * 256 + wc * 64 + n * 16 + (l & 15);
      if constexpr (EPI == 0) {
        int part = col >> 9, nn = col & 511;
        int hh = nn >> 6, hd = nn & 63;
        int b = row0 >> 12, sidx0 = row0 & 4095;
        if (part < 2) {
#pragma unroll
          for (int j = 0; j < 4; ++j)
            ob[((((size_t)part * NB + b) * NH + hh) * NS + sidx0 + j) * NHD + hd] =
                f2b(acc[m][n][j]);
        } else {
          ushort4 o;
          o.x = f2b(acc[m][n][0]);
          o.y = f2b(acc[m][n][1]);
          o.z = f2b(acc[m][n][2]);
          o.w = f2b(acc[m][n][3]);
          *(ushort4*)&ob[(size_t)2 * NB * NH * NS * NHD +
                         (((size_t)b * NH + hh) * NHD + hd) * NS + sidx0] = o;
        }
      } else {
#pragma unroll
        for (int j = 0; j < 4; ++j) {
          size_t i = (size_t)(row0 + j) * NMLP + col;
          ob[i] = f2b(geluf(acc[m][n][j] + bias[col]));
        }
      }
    }
}

// ---------------- 128x128 MFMA GEMM (4 waves, BK=64, dbuf, swizzled) ----------------
template <int EPI>
__global__ __launch_bounds__(256) void gemm_bt(const unsigned short* __restrict__ A,
                                               const unsigned short* __restrict__ Bt,
                                               int M, int N, int K,
                                               float* __restrict__ of,
                                               const float* __restrict__ addf,
                                               const float* __restrict__ bias) {
  __shared__ unsigned short lA[2][128 * 64];
  __shared__ unsigned short lB[2][128 * 64];
  const int t = threadIdx.x;
  const int l = t & 63, w = t >> 6;
  const int wr = w >> 1, wc = w & 1;
  const int gx = gridDim.x;
  const int nwg = gx * gridDim.y;
  const int fid = blockIdx.y * gx + blockIdx.x;
  const int q8 = nwg >> 3, r8 = nwg & 7, xcd = fid & 7, idx = fid >> 3;
  const int lid = (xcd < r8 ? xcd * (q8 + 1) : r8 * (q8 + 1) + (xcd - r8) * q8) + idx;
  const int bm = lid / gx, bn = lid % gx;
  const size_t rowBytes = (size_t)K * 2;
  const char* Ab = (const char*)A + (size_t)bm * 128 * rowBytes;
  const char* Bb = (const char*)Bt + (size_t)bn * 128 * rowBytes;
  const int srow0 = t >> 3;
  const int scb = (((t & 7) ^ ((t >> 3) & 7)) << 4);
  f32x4 acc[4][4] = {};

  auto stage = [&](int buf, int k0) {
    char* dA = (char*)&lA[buf][0] + t * 16;
    char* dB = (char*)&lB[buf][0] + t * 16;
#pragma unroll
    for (int i = 0; i < 4; ++i) {
      const size_t go = (size_t)(srow0 + i * 32) * rowBytes + 2 * k0 + scb;
      gload16(Ab + go, dA + i * 4096);
      gload16(Bb + go, dB + i * 4096);
    }
  };

  const int nkt = K >> 6;
  stage(0, 0);
  int cur = 0;
  for (int kt = 0; kt < nkt; ++kt) {
    if (kt + 1 < nkt) {
      stage(cur ^ 1, (kt + 1) * 64);
      asm volatile("s_waitcnt vmcnt(8)" ::: "memory");
    } else {
      asm volatile("s_waitcnt vmcnt(0)" ::: "memory");
    }
    __builtin_amdgcn_s_barrier();
    __builtin_amdgcn_sched_barrier(0);
#pragma unroll
    for (int ks = 0; ks < 2; ++ks) {
      const int xg = ((ks * 4 + (l >> 4)) ^ (l & 7)) * 8;
      bf16x8 aF[4], bF[4];
#pragma unroll
      for (int m = 0; m < 4; ++m)
        aF[m] = *(const bf16x8*)&lA[cur][(wr * 64 + m * 16 + (l & 15)) * 64 + xg];
#pragma unroll
      for (int n = 0; n < 4; ++n)
        bF[n] = *(const bf16x8*)&lB[cur][(wc * 64 + n * 16 + (l & 15)) * 64 + xg];
      __builtin_amdgcn_s_setprio(1);
#pragma unroll
      for (int m = 0; m < 4; ++m)
#pragma unroll
        for (int n = 0; n < 4; ++n)
          acc[m][n] = __builtin_amdgcn_mfma_f32_16x16x32_bf16(aF[m], bF[n], acc[m][n], 0, 0, 0);
      __builtin_amdgcn_s_setprio(0);
    }
    asm volatile("s_waitcnt lgkmcnt(0)" ::: "memory");
    __builtin_amdgcn_s_barrier();
    cur ^= 1;
  }
#pragma unroll
  for (int m = 0; m < 4; ++m)
#pragma unroll
    for (int n = 0; n < 4; ++n) {
      int row0 = bm * 128 + wr * 64 + m * 16 + (l >> 4) * 4;
      int col = bn * 128 + wc * 64 + n * 16 + (l & 15);
#pragma unroll
      for (int j = 0; j < 4; ++j) {
        int row = row0 + j;
        float v = acc[m][n][j];
        if constexpr (EPI == 1) {
          size_t i = (size_t)row * ND + col;
          of[i] = v + addf[i];
        } else {
          size_t i = (size_t)row * ND + col;
          of[i] = v + bias[col] + addf[i];
        }
      }
    }
}

// ---------------- block-sparse flash attention ----------------
// XCD-aware remap: hh = bid&7 (one head per XCD -> K/V working set ~4.2MB ~ L2);
// j = bid>>3: b = j>>5, qb = j<32 ? j : 63-j  (within-XCD blocks j and j+32 are
// complementary-work pairs on the same CU). Defer-max rescale (THR=8).
__global__ __launch_bounds__(512, 4) void attn_sparse(const unsigned short* __restrict__ qm,
                                                      const unsigned short* __restrict__ km,
                                                      const unsigned short* __restrict__ vTg,
                                                      unsigned short* __restrict__ ctx) {
  __shared__ unsigned short kl[128 * 72];
  __shared__ unsigned short vt[64 * 136];
  __shared__ unsigned short pl[8][16 * 72];
  const int t = threadIdx.x, l = t & 63, w = t >> 6;
  const int bid = blockIdx.x;
  const int hh = bid & 7;
  const int jj = bid >> 3;
  const int b = jj >> 5;
  const int qb = (jj < 32) ? jj : 63 - jj;
  const size_t bh = ((size_t)b * NH + hh) * NS;
  const size_t bhd = ((size_t)b * NH + hh) * NHD;
  const int qrow0 = qb * 128 + w * 16;
  bf16x8 qa[2];
#pragma unroll
  for (int ks = 0; ks < 2; ++ks)
    qa[ks] = *(const bf16x8*)&qm[(bh + qrow0 + (l & 15)) * NHD + ks * 32 + (l >> 4) * 8];
  f32x4 c[4] = {};
  float mrun[4], lrun[4];
#pragma unroll
  for (int j = 0; j < 4; ++j) { mrun[j] = -1e30f; lrun[j] = 0.0f; }

  const int nsum128 = qb >> 2, rem = qb & 3;
  const int nSumCh = nsum128 + (rem ? 1 : 0);
  const int nch = nSumCh + 1;
  const int kkey = t >> 2, kd = (t & 3) * 16;
  const int vd = t >> 3, vk = (t & 7) * 16;

  s16x8 kr0, kr1, vr0, vr1;
  auto issueLoads = [&](int c2) {
    int grK, sV;
    if (c2 < nSumCh) {
      grK = ((c2 << 2) + (kkey >> 5)) * 128 + 96 + (kkey & 31);
      sV = ((c2 << 2) + (vk >> 5)) * 128 + 96 + (vk & 31);
    } else {
      grK = qb * 128 + kkey;
      sV = qb * 128 + vk;
    }
    const unsigned short* kp = &km[(bh + grK) * NHD + kd];
    kr0 = *(const s16x8*)kp;
    kr1 = *(const s16x8*)(kp + 8);
    const unsigned short* vp = &vTg[(bhd + vd) * NS + sV];
    vr0 = *(const s16x8*)vp;
    vr1 = *(const s16x8*)(vp + 8);
  };

  issueLoads(0);
  for (int ch = 0; ch < nch; ++ch) {
    if (ch) {
      asm volatile("s_waitcnt lgkmcnt(0)" ::: "memory");
      __builtin_amdgcn_s_barrier();
    }
    *(s16x8*)&kl[kkey * 72 + kd] = kr0;
    *(s16x8*)&kl[kkey * 72 + kd + 8] = kr1;
    *(s16x8*)&vt[vd * 136 + vk] = vr0;
    *(s16x8*)&vt[vd * 136 + vk + 8] = vr1;
    asm volatile("s_waitcnt lgkmcnt(0)" ::: "memory");
    __builtin_amdgcn_s_barrier();
    __builtin_amdgcn_sched_barrier(0);
    if (ch + 1 < nch) issueLoads(ch + 1);

    const bool isLocal = (ch == nch - 1);
    const bool isRem = (rem != 0) && !isLocal && (ch == nsum128);
    const int nT = isLocal ? (w + 1) : (isRem ? 2 * rem : 8);
    const int nTpl = isLocal ? ((w | 1) + 1) : nT;
    const int nKs = nTpl >> 1;

    f32x4 sf[8];
#pragma unroll
    for (int n = 0; n < 8; ++n) {
      if (n < nT) {
        const bf16x8 k0 = *(const bf16x8*)&kl[(n * 16 + (l & 15)) * 72 + (l >> 4) * 8];
        const bf16x8 k1 = *(const bf16x8*)&kl[(n * 16 + (l & 15)) * 72 + 32 + (l >> 4) * 8];
        f32x4 a = {};
        a = __builtin_amdgcn_mfma_f32_16x16x32_bf16(qa[0], k0, a, 0, 0, 0);
        a = __builtin_amdgcn_mfma_f32_16x16x32_bf16(qa[1], k1, a, 0, 0, 0);
        if (isLocal && n == w) {
#pragma unroll
          for (int j = 0; j < 4; ++j)
            if ((l & 15) > (l >> 4) * 4 + j) a[j] = -1e9f;
        }
        sf[n] = a;
      }
    }
    float cm[4];
#pragma unroll
    for (int j = 0; j < 4; ++j) cm[j] = -1e30f;
#pragma unroll
    for (int n = 0; n < 8; ++n)
      if (n < nT)
#pragma unroll
        for (int j = 0; j < 4; ++j) cm[j] = fmaxf(cm[j], sf[n][j]);
#pragma unroll
    for (int j = 0; j < 4; ++j) {
      cm[j] = fmaxf(cm[j], __shfl_xor(cm[j], 1));
      cm[j] = fmaxf(cm[j], __shfl_xor(cm[j], 2));
      cm[j] = fmaxf(cm[j], __shfl_xor(cm[j], 4));
      cm[j] = fmaxf(cm[j], __shfl_xor(cm[j], 8));
    }
    // defer-max: only rescale when a row's max grew past mrun + 8
    bool need = false;
#pragma unroll
    for (int j = 0; j < 4; ++j) need |= (cm[j] > mrun[j] + 8.0f);
    if (__any(need)) {
      float al[4];
#pragma unroll
      for (int j = 0; j < 4; ++j) {
        float nm = fmaxf(mrun[j], cm[j]);
        al[j] = __expf(mrun[j] - nm);
        mrun[j] = nm;
      }
#pragma unroll
      for (int n = 0; n < 4; ++n)
#pragma unroll
        for (int j = 0; j < 4; ++j) c[n][j] *= al[j];
#pragma unroll
      for (int j = 0; j < 4; ++j) lrun[j] *= al[j];
    }
    float rs[4] = {0.f, 0.f, 0.f, 0.f};
#pragma unroll
    for (int n = 0; n < 8; ++n)
      if (n < nT)
#pragma unroll
        for (int j = 0; j < 4; ++j) {
          float p = __expf(sf[n][j] - mrun[j]);
          sf[n][j] = p;
          rs[j] += p;
        }
#pragma unroll
    for (int j = 0; j < 4; ++j) {
      rs[j] += __shfl_xor(rs[j], 1);
      rs[j] += __shfl_xor(rs[j], 2);
      rs[j] += __shfl_xor(rs[j], 4);
      rs[j] += __shfl_xor(rs[j], 8);
      lrun[j] += rs[j];
    }
#pragma unroll
    for (int h = 0; h < 2; ++h) {
      if (h * 4 < nTpl) {
#pragma unroll
        for (int n2 = 0; n2 < 4; ++n2) {
          const int n = h * 4 + n2;
#pragma unroll
          for (int j = 0; j < 4; ++j) {
            if (n < nTpl) {
              unsigned short pv = 0;
              if (n < nT) pv = f2b(sf[n][j]);
              pl[w][((l >> 4) * 4 + j) * 72 + n2 * 16 + (l & 15)] = pv;
            }
          }
        }
#pragma unroll
        for (int ks2 = 0; ks2 < 2; ++ks2) {
          const int ks = h * 2 + ks2;
          if (ks < nKs) {
            const bf16x8 pa = *(const bf16x8*)&pl[w][(l & 15) * 72 + ks2 * 32 + (l >> 4) * 8];
#pragma unroll
            for (int nd = 0; nd < 4; ++nd) {
              const bf16x8 vb =
                  *(const bf16x8*)&vt[(nd * 16 + (l & 15)) * 136 + ks * 32 + (l >> 4) * 8];
              c[nd] = __builtin_amdgcn_mfma_f32_16x16x32_bf16(pa, vb, c[nd], 0, 0, 0);
            }
          }
        }
      }
    }
  }
  float rinv[4];
#pragma unroll
  for (int j = 0; j < 4; ++j) rinv[j] = 1.0f / lrun[j];
#pragma unroll
  for (int n = 0; n < 4; ++n)
#pragma unroll
    for (int j = 0; j < 4; ++j) {
      int srow = qrow0 + (l >> 4) * 4 + j;
      int col = n * 16 + (l & 15);
      ctx[((size_t)b * NS + srow) * ND + hh * NHD + col] = f2b(c[n][j] * rinv[j]);
    }
}

extern "C" void kernel_launch(void* const* d_in, const int* in_sizes, int n_in,
                              void* d_out, int out_size, void* d_ws, size_t ws_size,
                              hipStream_t stream) {
  (void)in_sizes; (void)n_in; (void)out_size; (void)ws_size;
  const float* inputs = (const float*)d_in[0];
  const float* ln1s = (const float*)d_in[1];
  const float* ln1b = (const float*)d_in[2];
  const float* wq = (const float*)d_in[3];
  const float* wk = (const float*)d_in[4];
  const float* wv = (const float*)d_in[5];
  const float* wo = (const float*)d_in[6];
  const float* ln2s = (const float*)d_in[7];
  const float* ln2b = (const float*)d_in[8];
  const float* w1 = (const float*)d_in[9];
  const float* b1 = (const float*)d_in[10];
  const float* w2 = (const float*)d_in[11];
  const float* b2 = (const float*)d_in[12];
  float* out = (float*)d_out;

  // workspace layout (~102 MB)
  unsigned short* xln = (unsigned short*)d_ws;                 // 8192*512 bf16
  unsigned short* xln2 = xln + (size_t)8192 * 512;             // 8192*512
  unsigned short* ctx = xln2 + (size_t)8192 * 512;             // 8192*512
  unsigned short* qkv = ctx + (size_t)8192 * 512;              // 3 * 8192*512 (Q, K, V^T)
  float* xres = (float*)(qkv + (size_t)3 * 8192 * 512);        // 8192*512 fp32
  unsigned short* hbuf = (unsigned short*)(xres + (size_t)8192 * 512);  // 8192*2048
  unsigned short* qkvT = hbuf + (size_t)8192 * 2048;           // 1536*512
  unsigned short* woT = qkvT + (size_t)1536 * 512;             // 512*512
  unsigned short* w1T = woT + (size_t)512 * 512;               // 2048*512
  unsigned short* w2T = w1T + (size_t)2048 * 512;              // 512*2048

  prep_weights<<<768, 256, 0, stream>>>(wq, wk, wv, wo, w1, w2, qkvT, woT, w1T, w2T);
  ln_bf16<<<2048, 256, 0, stream>>>(inputs, ln1s, ln1b, xln);
  gemm256<0><<<dim3(6, 32), 512, 0, stream>>>(xln, qkvT, 8192, 1536, 512, qkv, nullptr);
  attn_sparse<<<512, 512, 0, stream>>>(qkv, qkv + (size_t)8192 * 512,
                                       qkv + (size_t)2 * 8192 * 512, ctx);
  gemm_bt<1><<<dim3(4, 64), 256, 0, stream>>>(ctx, woT, 8192, 512, 512,
                                              xres, inputs, nullptr);
  ln_bf16<<<2048, 256, 0, stream>>>(xres, ln2s, ln2b, xln2);
  gemm256<2><<<dim3(8, 32), 512, 0, stream>>>(xln2, w1T, 8192, 2048, 512, hbuf, b1);
  gemm_bt<3><<<dim3(4, 64), 256, 0, stream>>>(hbuf, w2T, 8192, 512, 2048,
                                              out, xres, b2);
}